// Round 5
// baseline (998.883 us; speedup 1.0000x reference)
//
#include <hip/hip_runtime.h>
#include <hip/hip_bf16.h>

#define B_ 8
#define N_ 2048
#define TN 64
#define TM 128

__global__ void k_transpose_x(const float* __restrict__ x, float* __restrict__ xt) {
    int i = blockIdx.x * 256 + threadIdx.x;
    if (i >= B_ * N_) return;
    int b = i >> 11, n = i & (N_ - 1);
    const float* src = x + (size_t)b * 3 * N_ + n;
    float* dst = xt + (size_t)i * 3;
    dst[0] = src[0];
    dst[1] = src[N_];
    dst[2] = src[2 * N_];
}

__global__ void k_sqnorm(const float* __restrict__ act, float* __restrict__ sq, int C) {
    int i = blockIdx.x * 256 + threadIdx.x;
    if (i >= B_ * N_) return;
    const float* r = act + (size_t)i * C;
    float s = 0.f;
    for (int c = 0; c < C; ++c) s += r[c] * r[c];
    sq[i] = s;
}

// Wt[k][o2], k<C, o2<ncols. Half-width packs select W rows [orow0, orow0+O).
// o2<O -> W[orow0+o2][k] (neighbor half), else W[orow0+o2-O][C+k] (center half).
__global__ void k_pack_w(const float* __restrict__ W, float* __restrict__ Wt,
                         int O, int C, int ncols, int wrow, int orow0) {
    int i = blockIdx.x * 256 + threadIdx.x;
    if (i >= C * ncols) return;
    int k = i / ncols, o2 = i % ncols;
    int o   = ((o2 < O) ? o2 : o2 - O) + orow0;
    int col = (o2 < O) ? k : (C + k);
    Wt[i] = W[(size_t)o * wrow + col];
}

__device__ __forceinline__ void ins4(float& v0, float& v1, float& v2, float& v3,
                                     int& i0, int& i1, int& i2, int& i3,
                                     float p, int m) {
    bool g3 = p > v3, g2 = p > v2, g1 = p > v1, g0 = p > v0;
    v3 = g2 ? v2 : (g3 ? p : v3); i3 = g2 ? i2 : (g3 ? m : i3);
    v2 = g1 ? v1 : (g2 ? p : v2); i2 = g1 ? i1 : (g2 ? m : i2);
    v1 = g0 ? v0 : (g1 ? p : v1); i1 = g0 ? i0 : (g1 ? m : i1);
    v0 = g0 ? p  : v0;            i0 = g0 ? m  : i0;
}

// Fused pairwise-distance GEMM + top-4 selection. Channel-chunked LDS staging:
// CHUNK=min(CP,64) keeps every instantiation's static LDS <= 52KB (C=128 was
// 102KB before). Accumulation order over channels is unchanged (ascending),
// so results are bit-identical to the unchunked version.
// Block: 64 n-rows; m-chunks of TM=128; thread (ng,mg) = 4 n-rows x 8 m.
template<int C, int CP>
__global__ __launch_bounds__(256) void k_knn_top4(
    const float* __restrict__ act, const float* __restrict__ sqg,
    int* __restrict__ idxo)
{
    constexpr int CHUNK = (CP < 64) ? CP : 64;
    constexpr int NCH   = CP / CHUNK;          // 1 (C<=64) or 2 (C=128)
    constexpr int S     = CHUNK + 4;
    constexpr int TILEF  = TN * S + TM * S + TN + TM;
    constexpr int MERGEF = 64 * 66 * 2;
    constexpr int LDSF   = TILEF > MERGEF ? TILEF : MERGEF;
    __shared__ float lds[LDSF];

    float* xn  = lds;
    float* xm  = lds + TN * S;
    float* sqn = xm + TM * S;
    float* sqm = sqn + TN;

    const int b  = blockIdx.x >> 5;          // N_/TN = 32 blocks per batch
    const int n0 = (blockIdx.x & 31) * TN;
    const int t  = threadIdx.x;
    const int ng = t >> 4;
    const int mg = t & 15;
    const float* ab = act + (size_t)b * N_ * C;
    constexpr int C4N = CHUNK >> 2;

    float tv[4][4];
    int   ti[4][4];
    #pragma unroll
    for (int j = 0; j < 4; ++j)
        #pragma unroll
        for (int q = 0; q < 4; ++q) { tv[j][q] = -3.4e38f; ti[j][q] = 0; }

    for (int m0 = 0; m0 < N_; m0 += TM) {
        float acc[4][8];
        #pragma unroll
        for (int j = 0; j < 4; ++j)
            #pragma unroll
            for (int i = 0; i < 8; ++i) acc[j][i] = 0.f;

        for (int ch = 0; ch < NCH; ++ch) {
            const int cbase = ch * CHUNK;
            __syncthreads();   // also protects sqm/xn/xm reuse across m0 iters
            for (int e = t; e < TN * C4N; e += 256) {
                int r = e / C4N, c4 = (e % C4N) << 2;
                const float* src = ab + (size_t)(n0 + r) * C + cbase + c4;
                float4 v;
                if constexpr (CP == C) {
                    v = *(const float4*)src;
                } else {
                    v.x = (cbase + c4 + 0 < C) ? src[0] : 0.f;
                    v.y = (cbase + c4 + 1 < C) ? src[1] : 0.f;
                    v.z = (cbase + c4 + 2 < C) ? src[2] : 0.f;
                    v.w = (cbase + c4 + 3 < C) ? src[3] : 0.f;
                }
                *(float4*)&xn[r * S + c4] = v;
            }
            for (int e = t; e < TM * C4N; e += 256) {
                int r = e / C4N, c4 = (e % C4N) << 2;
                const float* src = ab + (size_t)(m0 + r) * C + cbase + c4;
                float4 v;
                if constexpr (CP == C) {
                    v = *(const float4*)src;
                } else {
                    v.x = (cbase + c4 + 0 < C) ? src[0] : 0.f;
                    v.y = (cbase + c4 + 1 < C) ? src[1] : 0.f;
                    v.z = (cbase + c4 + 2 < C) ? src[2] : 0.f;
                    v.w = (cbase + c4 + 3 < C) ? src[3] : 0.f;
                }
                *(float4*)&xm[r * S + c4] = v;
            }
            if (ch == 0) {
                if (t < TN) sqn[t] = sqg[b * N_ + n0 + t];
                if (t < TM) sqm[t] = sqg[b * N_ + m0 + t];
            }
            __syncthreads();

            for (int c4 = 0; c4 < CHUNK; c4 += 4) {
                float4 a[4], bb[8];
                #pragma unroll
                for (int j = 0; j < 4; ++j) a[j] = *(float4*)&xn[(ng * 4 + j) * S + c4];
                #pragma unroll
                for (int i = 0; i < 8; ++i) bb[i] = *(float4*)&xm[(i * 16 + mg) * S + c4];
                #pragma unroll
                for (int j = 0; j < 4; ++j)
                    #pragma unroll
                    for (int i = 0; i < 8; ++i)
                        acc[j][i] += a[j].x * bb[i].x + a[j].y * bb[i].y
                                   + a[j].z * bb[i].z + a[j].w * bb[i].w;
            }
        }

        float sn[4];
        #pragma unroll
        for (int j = 0; j < 4; ++j) sn[j] = sqn[ng * 4 + j];
        #pragma unroll
        for (int i = 0; i < 8; ++i) {
            int   m  = m0 + i * 16 + mg;
            float sm = sqm[i * 16 + mg];
            #pragma unroll
            for (int j = 0; j < 4; ++j) {
                float pd = 2.f * acc[j][i] - sn[j] - sm;
                ins4(tv[j][0], tv[j][1], tv[j][2], tv[j][3],
                     ti[j][0], ti[j][1], ti[j][2], ti[j][3], pd, m);
            }
        }
    }

    __syncthreads();
    // merge scratch overlays the (now dead) tile area: val[64][66] + idx[64][66]
    float* mval = lds;
    int*   mind = (int*)(lds + 64 * 66);
    #pragma unroll
    for (int j = 0; j < 4; ++j) {
        int row = ng * 4 + j;
        #pragma unroll
        for (int q = 0; q < 4; ++q) {
            mval[row * 66 + mg * 4 + q] = tv[j][q];
            mind[row * 66 + mg * 4 + q] = ti[j][q];
        }
    }
    __syncthreads();
    if (t < TN) {
        float v0 = -3.4e38f, v1 = v0, v2 = v0, v3 = v0;
        int   i0 = 0, i1 = 0, i2 = 0, i3 = 0;
        for (int j = 0; j < 64; ++j) {
            float p = mval[t * 66 + j];
            int   m = mind[t * 66 + j];
            ins4(v0, v1, v2, v3, i0, i1, i2, i3, p, m);
        }
        int* op = idxo + ((size_t)b * N_ + n0 + t) * 4;
        op[0] = i0; op[1] = i1; op[2] = i2; op[3] = i3;
    }
}

// Tiled f32 GEMM: D(R x ncols) = A(R x K) * Bt(K x ncols). 64x64 tile, 4x4 micro.
// MODE 0: plain f32 store, row-major (R x ncols).
// MODE 1: final layer — A gathered from x1..x4 (K split 64/64/128/256); store
// FLOAT32 (round-4 theory: d_out is f32 per reference dtype) transposed to
// (B, 512, N), coalesced along n via an LDS transpose of the 64x64 tile.
template<int MODE>
__global__ __launch_bounds__(256) void k_gemm(
    const float* __restrict__ A, int lda,
    const float* __restrict__ Bt, int ldb,
    float* __restrict__ D, int ldd, int K,
    const float* __restrict__ g1, const float* __restrict__ g2,
    const float* __restrict__ g3, const float* __restrict__ g4)
{
    __shared__ float smem[2 * 32 * 68];          // At | Bs ; reused as 64x65 T
    float* At = smem;                             // At[k][r]
    float* Bs = smem + 32 * 68;                   // Bs[k][c]
    const int r0 = blockIdx.x * 64;
    const int c0 = blockIdx.y * 64;
    const int t  = threadIdx.x;
    const int tr = t >> 4, tc = t & 15;
    float acc[4][4];
    #pragma unroll
    for (int j = 0; j < 4; ++j)
        #pragma unroll
        for (int i = 0; i < 4; ++i) acc[j][i] = 0.f;

    for (int k0 = 0; k0 < K; k0 += 32) {
        const float* Ab; int Al, koff;
        if (MODE == 1) {
            if      (k0 < 64)  { Ab = g1; Al = 64;  koff = 0;   }
            else if (k0 < 128) { Ab = g2; Al = 64;  koff = 64;  }
            else if (k0 < 256) { Ab = g3; Al = 128; koff = 128; }
            else               { Ab = g4; Al = 256; koff = 256; }
        } else { Ab = A; Al = lda; koff = 0; }

        for (int e = t; e < 64 * 32; e += 256) {
            int r = e >> 5, kk = e & 31;
            int kg = k0 + kk;
            float v = (kg < K) ? Ab[(size_t)(r0 + r) * Al + (kg - koff)] : 0.f;
            At[kk * 68 + r] = v;
        }
        for (int e = t; e < 32 * 16; e += 256) {
            int kk = e >> 4, c4 = (e & 15) << 2;
            int kg = k0 + kk;
            float4 v = {0.f, 0.f, 0.f, 0.f};
            if (kg < K) v = *(const float4*)&Bt[(size_t)kg * ldb + c0 + c4];
            *(float4*)&Bs[kk * 68 + c4] = v;
        }
        __syncthreads();
        for (int kk = 0; kk < 32; ++kk) {
            float4 av = *(float4*)&At[kk * 68 + tr * 4];
            float4 bv = *(float4*)&Bs[kk * 68 + tc * 4];
            const float* ap = (const float*)&av;
            const float* bp = (const float*)&bv;
            #pragma unroll
            for (int j = 0; j < 4; ++j)
                #pragma unroll
                for (int i = 0; i < 4; ++i) acc[j][i] += ap[j] * bp[i];
        }
        __syncthreads();
    }

    if (MODE == 0) {
        #pragma unroll
        for (int j = 0; j < 4; ++j) {
            size_t r = r0 + tr * 4 + j;
            float4 v; v.x = acc[j][0]; v.y = acc[j][1]; v.z = acc[j][2]; v.w = acc[j][3];
            *(float4*)&D[r * ldd + c0 + tc * 4] = v;
        }
    } else {
        // transpose 64x64 tile in LDS: T[o_local][r_local], then coalesced
        // f32 stores along n. Block never straddles a batch (2048 % 64 == 0).
        float* T = smem;                          // 64 x 65
        #pragma unroll
        for (int j = 0; j < 4; ++j)
            #pragma unroll
            for (int i = 0; i < 4; ++i)
                T[(tc * 4 + i) * 65 + tr * 4 + j] = acc[j][i];
        __syncthreads();
        int b  = r0 >> 11, n0l = r0 & (N_ - 1);
        for (int e = t; e < 64 * 64; e += 256) {
            int row = e >> 6, col = e & 63;       // row: o-local, col: n-local
            D[((size_t)b * 512 + c0 + row) * N_ + n0l + col] = T[row * 65 + col];
        }
    }
}

// acto[rn*ostride + ocol0 + o] = relu( max_k dot[b, idx[k], o] + dot[rn, O+o] ), o<O
__global__ void k_gather_max(const float* __restrict__ dot, const int* __restrict__ idxg,
                             float* __restrict__ acto, int O, int ostride, int ocol0) {
    int i = blockIdx.x * 256 + threadIdx.x;
    if (i >= B_ * N_ * O) return;
    int o  = i % O;
    int rn = i / O;
    int b  = rn >> 11;
    const int* ip = idxg + (size_t)rn * 4;
    int twoO = O * 2;
    size_t bbase = (size_t)b * N_ * twoO;
    float ctr = dot[(size_t)rn * twoO + O + o];
    float m0 = dot[bbase + (size_t)ip[0] * twoO + o];
    float m1 = dot[bbase + (size_t)ip[1] * twoO + o];
    float m2 = dot[bbase + (size_t)ip[2] * twoO + o];
    float m3 = dot[bbase + (size_t)ip[3] * twoO + o];
    float mx = fmaxf(fmaxf(m0, m1), fmaxf(m2, m3));
    acto[(size_t)rn * ostride + ocol0 + o] = fmaxf(mx + ctr, 0.f);
}

extern "C" void kernel_launch(void* const* d_in, const int* in_sizes, int n_in,
                              void* d_out, int out_size, void* d_ws, size_t ws_size,
                              hipStream_t stream) {
    const float* x  = (const float*)d_in[0];
    const float* W1 = (const float*)d_in[1];
    const float* W2 = (const float*)d_in[2];
    const float* W3 = (const float*)d_in[3];
    const float* W4 = (const float*)d_in[4];
    const float* W5 = (const float*)d_in[5];

    // Compact layout: 12,976,128 floats = 49.5 MiB total.
    float* ws  = (float*)d_ws;
    float* x1  = ws;                          // 16384*64   = 1048576
    float* x2  = x1 + 1048576;                // 16384*64   = 1048576
    float* x3  = x2 + 1048576;                // 16384*128  = 2097152
    float* x4  = x3 + 2097152;                // 16384*256  = 4194304
    float* dot = x4 + 4194304;                // max 16384*256 = 4194304
    float* xt0 = dot + 4194304;               // 49152
    float* sq  = xt0 + 49152;                 // 16384
    int*   idx = (int*)(sq + 16384);          // 65536 ints
    float* wt  = sq + 16384 + 65536;          // max 512*512 = 262144

    k_transpose_x<<<64, 256, 0, stream>>>(x, xt0);

    // ---- layer 1: C=3, O=64 ----
    {
        const float* actin = xt0; int C = 3, O = 64, ncols = 2 * O;
        k_sqnorm<<<64, 256, 0, stream>>>(actin, sq, C);
        k_knn_top4<3, 4><<<256, 256, 0, stream>>>(actin, sq, idx);
        k_pack_w<<<(C * ncols + 255) / 256, 256, 0, stream>>>(W1, wt, O, C, ncols, 2 * C, 0);
        dim3 g((B_ * N_) / 64, ncols / 64);
        k_gemm<0><<<g, 256, 0, stream>>>(actin, C, wt, ncols, dot, ncols, C,
                                         nullptr, nullptr, nullptr, nullptr);
        k_gather_max<<<(B_ * N_ * O + 255) / 256, 256, 0, stream>>>(dot, idx, x1, O, O, 0);
    }
    // ---- layer 2: C=64, O=64 ----
    {
        const float* actin = x1; int C = 64, O = 64, ncols = 2 * O;
        k_sqnorm<<<64, 256, 0, stream>>>(actin, sq, C);
        k_knn_top4<64, 64><<<256, 256, 0, stream>>>(actin, sq, idx);
        k_pack_w<<<(C * ncols + 255) / 256, 256, 0, stream>>>(W2, wt, O, C, ncols, 2 * C, 0);
        dim3 g((B_ * N_) / 64, ncols / 64);
        k_gemm<0><<<g, 256, 0, stream>>>(actin, C, wt, ncols, dot, ncols, C,
                                         nullptr, nullptr, nullptr, nullptr);
        k_gather_max<<<(B_ * N_ * O + 255) / 256, 256, 0, stream>>>(dot, idx, x2, O, O, 0);
    }
    // ---- layer 3: C=64, O=128 ----
    {
        const float* actin = x2; int C = 64, O = 128, ncols = 2 * O;
        k_sqnorm<<<64, 256, 0, stream>>>(actin, sq, C);
        k_knn_top4<64, 64><<<256, 256, 0, stream>>>(actin, sq, idx);
        k_pack_w<<<(C * ncols + 255) / 256, 256, 0, stream>>>(W3, wt, O, C, ncols, 2 * C, 0);
        dim3 g((B_ * N_) / 64, ncols / 64);
        k_gemm<0><<<g, 256, 0, stream>>>(actin, C, wt, ncols, dot, ncols, C,
                                         nullptr, nullptr, nullptr, nullptr);
        k_gather_max<<<(B_ * N_ * O + 255) / 256, 256, 0, stream>>>(dot, idx, x3, O, O, 0);
    }
    // ---- layer 4: C=128, O=256 — two 128-output halves so dot <= 16 MB ----
    {
        const float* actin = x3; int C = 128;
        k_sqnorm<<<64, 256, 0, stream>>>(actin, sq, C);
        k_knn_top4<128, 128><<<256, 256, 0, stream>>>(actin, sq, idx);
        for (int oh = 0; oh < 2; ++oh) {
            int Oh = 128, ncols = 2 * Oh, o0 = oh * 128;
            k_pack_w<<<(C * ncols + 255) / 256, 256, 0, stream>>>(W4, wt, Oh, C, ncols, 2 * C, o0);
            dim3 g((B_ * N_) / 64, ncols / 64);
            k_gemm<0><<<g, 256, 0, stream>>>(actin, C, wt, ncols, dot, ncols, C,
                                             nullptr, nullptr, nullptr, nullptr);
            k_gather_max<<<(B_ * N_ * Oh + 255) / 256, 256, 0, stream>>>(dot, idx, x4, Oh, 256, o0);
        }
    }

    // ---- final: out = W5 * concat(x1,x2,x3,x4), f32 out, (B,512,N) ----
    k_pack_w<<<(512 * 512 + 255) / 256, 256, 0, stream>>>(W5, wt, 512, 512, 512, 512, 0);
    dim3 gf((B_ * N_) / 64, 512 / 64);
    k_gemm<1><<<gf, 256, 0, stream>>>(nullptr, 0, wt, 512, (float*)d_out, 0, 512,
                                      x1, x2, x3, x4);
}

// Round 6
// 785.142 us; speedup vs baseline: 1.2722x; 1.2722x over previous
//
#include <hip/hip_runtime.h>
#include <hip/hip_bf16.h>

#define B_ 8
#define N_ 2048
#define TN 64
#define TM 128
#define SEG 4

__global__ void k_transpose_x(const float* __restrict__ x, float* __restrict__ xt) {
    int i = blockIdx.x * 256 + threadIdx.x;
    if (i >= B_ * N_) return;
    int b = i >> 11, n = i & (N_ - 1);
    const float* src = x + (size_t)b * 3 * N_ + n;
    float* dst = xt + (size_t)i * 3;
    dst[0] = src[0];
    dst[1] = src[N_];
    dst[2] = src[2 * N_];
}

__global__ void k_sqnorm(const float* __restrict__ act, float* __restrict__ sq, int C) {
    int i = blockIdx.x * 256 + threadIdx.x;
    if (i >= B_ * N_) return;
    const float* r = act + (size_t)i * C;
    float s = 0.f;
    for (int c = 0; c < C; ++c) s += r[c] * r[c];
    sq[i] = s;
}

// Wt[k][o2], k<C, o2<ncols. Half-width packs select W rows [orow0, orow0+O).
__global__ void k_pack_w(const float* __restrict__ W, float* __restrict__ Wt,
                         int O, int C, int ncols, int wrow, int orow0) {
    int i = blockIdx.x * 256 + threadIdx.x;
    if (i >= C * ncols) return;
    int k = i / ncols, o2 = i % ncols;
    int o   = ((o2 < O) ? o2 : o2 - O) + orow0;
    int col = (o2 < O) ? k : (C + k);
    Wt[i] = W[(size_t)o * wrow + col];
}

__device__ __forceinline__ void ins4(float& v0, float& v1, float& v2, float& v3,
                                     int& i0, int& i1, int& i2, int& i3,
                                     float p, int m) {
    bool g3 = p > v3, g2 = p > v2, g1 = p > v1, g0 = p > v0;
    v3 = g2 ? v2 : (g3 ? p : v3); i3 = g2 ? i2 : (g3 ? m : i3);
    v2 = g1 ? v1 : (g2 ? p : v2); i2 = g1 ? i1 : (g2 ? m : i2);
    v1 = g0 ? v0 : (g1 ? p : v1); i1 = g0 ? i0 : (g1 ? m : i1);
    v0 = g0 ? p  : v0;            i0 = g0 ? m  : i0;
}

// Segmented pairwise-distance + per-segment top-4.
// Round-5 occupancy fix: grid = B*32*SEG (1024 blocks, was 256 = 1 block/CU,
// OccupancyPercent 11.5, VALUBusy 42 -> latency-bound). CHUNK=32 + shuffle
// merge cuts static LDS 53KB -> 27.8KB (HW cap 5 blocks/CU); 16 waves/CU.
// Block: 64 n-rows x 512 m's; thread (ng,mg) = 4 n-rows x 8 m (m = i*16+mg).
template<int C, int CP>
__global__ __launch_bounds__(256) void k_knn_part(
    const float* __restrict__ act, const float* __restrict__ sqg,
    float* __restrict__ pval, int* __restrict__ pidx)
{
    constexpr int CHUNK = (CP < 32) ? CP : 32;
    constexpr int NCH   = CP / CHUNK;
    constexpr int S     = CHUNK + 4;
    __shared__ float xn[TN * S];
    __shared__ float xm[TM * S];
    __shared__ float sqn[TN];
    __shared__ float sqm[TM];

    const int seg = blockIdx.x & (SEG - 1);
    const int nb  = (blockIdx.x >> 2) & 31;
    const int b   = blockIdx.x >> 7;          // / (SEG*32)
    const int n0  = nb * TN;
    const int t   = threadIdx.x;
    const int ng  = t >> 4;
    const int mg  = t & 15;
    const float* ab = act + (size_t)b * N_ * C;
    constexpr int C4N = CHUNK >> 2;

    float tv[4][4];
    int   ti[4][4];
    #pragma unroll
    for (int j = 0; j < 4; ++j)
        #pragma unroll
        for (int q = 0; q < 4; ++q) { tv[j][q] = -3.4e38f; ti[j][q] = 0; }

    const int mend = (seg + 1) * (N_ / SEG);
    for (int m0 = seg * (N_ / SEG); m0 < mend; m0 += TM) {
        float acc[4][8];
        #pragma unroll
        for (int j = 0; j < 4; ++j)
            #pragma unroll
            for (int i = 0; i < 8; ++i) acc[j][i] = 0.f;

        for (int ch = 0; ch < NCH; ++ch) {
            const int cbase = ch * CHUNK;
            __syncthreads();   // protects xn/xm/sq reuse across chunks/m0
            for (int e = t; e < TN * C4N; e += 256) {
                int r = e / C4N, c4 = (e % C4N) << 2;
                const float* src = ab + (size_t)(n0 + r) * C + cbase + c4;
                float4 v;
                if constexpr (CP == C) {
                    v = *(const float4*)src;
                } else {
                    v.x = (cbase + c4 + 0 < C) ? src[0] : 0.f;
                    v.y = (cbase + c4 + 1 < C) ? src[1] : 0.f;
                    v.z = (cbase + c4 + 2 < C) ? src[2] : 0.f;
                    v.w = (cbase + c4 + 3 < C) ? src[3] : 0.f;
                }
                *(float4*)&xn[r * S + c4] = v;
            }
            for (int e = t; e < TM * C4N; e += 256) {
                int r = e / C4N, c4 = (e % C4N) << 2;
                const float* src = ab + (size_t)(m0 + r) * C + cbase + c4;
                float4 v;
                if constexpr (CP == C) {
                    v = *(const float4*)src;
                } else {
                    v.x = (cbase + c4 + 0 < C) ? src[0] : 0.f;
                    v.y = (cbase + c4 + 1 < C) ? src[1] : 0.f;
                    v.z = (cbase + c4 + 2 < C) ? src[2] : 0.f;
                    v.w = (cbase + c4 + 3 < C) ? src[3] : 0.f;
                }
                *(float4*)&xm[r * S + c4] = v;
            }
            if (ch == 0) {
                if (t < TN) sqn[t] = sqg[b * N_ + n0 + t];
                if (t < TM) sqm[t] = sqg[b * N_ + m0 + t];
            }
            __syncthreads();

            for (int c4 = 0; c4 < CHUNK; c4 += 4) {
                float4 a[4], bb[8];
                #pragma unroll
                for (int j = 0; j < 4; ++j) a[j] = *(float4*)&xn[(ng * 4 + j) * S + c4];
                #pragma unroll
                for (int i = 0; i < 8; ++i) bb[i] = *(float4*)&xm[(i * 16 + mg) * S + c4];
                #pragma unroll
                for (int j = 0; j < 4; ++j)
                    #pragma unroll
                    for (int i = 0; i < 8; ++i)
                        acc[j][i] += a[j].x * bb[i].x + a[j].y * bb[i].y
                                   + a[j].z * bb[i].z + a[j].w * bb[i].w;
            }
        }

        float sn[4];
        #pragma unroll
        for (int j = 0; j < 4; ++j) sn[j] = sqn[ng * 4 + j];
        #pragma unroll
        for (int i = 0; i < 8; ++i) {
            int   m  = m0 + i * 16 + mg;
            float sm = sqm[i * 16 + mg];
            #pragma unroll
            for (int j = 0; j < 4; ++j) {
                float pd = 2.f * acc[j][i] - sn[j] - sm;
                ins4(tv[j][0], tv[j][1], tv[j][2], tv[j][3],
                     ti[j][0], ti[j][1], ti[j][2], ti[j][3], pd, m);
            }
        }
    }

    // butterfly merge across the 16 mg-lanes (contiguous within a wave)
    #pragma unroll
    for (int j = 0; j < 4; ++j) {
        float v0 = tv[j][0], v1 = tv[j][1], v2 = tv[j][2], v3 = tv[j][3];
        int   i0 = ti[j][0], i1 = ti[j][1], i2 = ti[j][2], i3 = ti[j][3];
        #pragma unroll
        for (int st = 1; st < 16; st <<= 1) {
            float w0 = __shfl_xor(v0, st), w1 = __shfl_xor(v1, st);
            float w2 = __shfl_xor(v2, st), w3 = __shfl_xor(v3, st);
            int   j0 = __shfl_xor(i0, st), j1 = __shfl_xor(i1, st);
            int   j2 = __shfl_xor(i2, st), j3 = __shfl_xor(i3, st);
            ins4(v0, v1, v2, v3, i0, i1, i2, i3, w0, j0);
            ins4(v0, v1, v2, v3, i0, i1, i2, i3, w1, j1);
            ins4(v0, v1, v2, v3, i0, i1, i2, i3, w2, j2);
            ins4(v0, v1, v2, v3, i0, i1, i2, i3, w3, j3);
        }
        if (mg == 0) {
            size_t base = ((size_t)b * N_ + n0 + ng * 4 + j) * (SEG * 4) + seg * 4;
            pval[base + 0] = v0; pval[base + 1] = v1;
            pval[base + 2] = v2; pval[base + 3] = v3;
            pidx[base + 0] = i0; pidx[base + 1] = i1;
            pidx[base + 2] = i2; pidx[base + 3] = i3;
        }
    }
}

// merge SEG per-segment top-4 lists (ascending seg order) -> final top-4 idx
__global__ void k_knn_merge(const float* __restrict__ pval, const int* __restrict__ pidx,
                            int* __restrict__ idxo) {
    int rn = blockIdx.x * 256 + threadIdx.x;
    if (rn >= B_ * N_) return;
    const float* pv = pval + (size_t)rn * (SEG * 4);
    const int*   pi = pidx + (size_t)rn * (SEG * 4);
    float v0 = pv[0], v1 = pv[1], v2 = pv[2], v3 = pv[3];
    int   i0 = pi[0], i1 = pi[1], i2 = pi[2], i3 = pi[3];
    for (int s = 1; s < SEG; ++s)
        #pragma unroll
        for (int q = 0; q < 4; ++q)
            ins4(v0, v1, v2, v3, i0, i1, i2, i3, pv[s * 4 + q], pi[s * 4 + q]);
    int* op = idxo + (size_t)rn * 4;
    op[0] = i0; op[1] = i1; op[2] = i2; op[3] = i3;
}

// Tiled f32 GEMM: D(R x ncols) = A(R x K) * Bt(K x ncols). 64x64 tile, 4x4 micro.
// MODE 0: plain f32 store. MODE 1: final layer — A gathered from x1..x4 (K split
// 64/64/128/256), f32 store transposed to (B, 512, N) via LDS tile transpose.
template<int MODE>
__global__ __launch_bounds__(256) void k_gemm(
    const float* __restrict__ A, int lda,
    const float* __restrict__ Bt, int ldb,
    float* __restrict__ D, int ldd, int K,
    const float* __restrict__ g1, const float* __restrict__ g2,
    const float* __restrict__ g3, const float* __restrict__ g4)
{
    __shared__ float smem[2 * 32 * 68];          // At | Bs ; reused as 64x65 T
    float* At = smem;                             // At[k][r]
    float* Bs = smem + 32 * 68;                   // Bs[k][c]
    const int r0 = blockIdx.x * 64;
    const int c0 = blockIdx.y * 64;
    const int t  = threadIdx.x;
    const int tr = t >> 4, tc = t & 15;
    float acc[4][4];
    #pragma unroll
    for (int j = 0; j < 4; ++j)
        #pragma unroll
        for (int i = 0; i < 4; ++i) acc[j][i] = 0.f;

    for (int k0 = 0; k0 < K; k0 += 32) {
        const float* Ab; int Al, koff;
        if (MODE == 1) {
            if      (k0 < 64)  { Ab = g1; Al = 64;  koff = 0;   }
            else if (k0 < 128) { Ab = g2; Al = 64;  koff = 64;  }
            else if (k0 < 256) { Ab = g3; Al = 128; koff = 128; }
            else               { Ab = g4; Al = 256; koff = 256; }
        } else { Ab = A; Al = lda; koff = 0; }

        for (int e = t; e < 64 * 32; e += 256) {
            int r = e >> 5, kk = e & 31;
            int kg = k0 + kk;
            float v = (kg < K) ? Ab[(size_t)(r0 + r) * Al + (kg - koff)] : 0.f;
            At[kk * 68 + r] = v;
        }
        for (int e = t; e < 32 * 16; e += 256) {
            int kk = e >> 4, c4 = (e & 15) << 2;
            int kg = k0 + kk;
            float4 v = {0.f, 0.f, 0.f, 0.f};
            if (kg < K) v = *(const float4*)&Bt[(size_t)kg * ldb + c0 + c4];
            *(float4*)&Bs[kk * 68 + c4] = v;
        }
        __syncthreads();
        for (int kk = 0; kk < 32; ++kk) {
            float4 av = *(float4*)&At[kk * 68 + tr * 4];
            float4 bv = *(float4*)&Bs[kk * 68 + tc * 4];
            const float* ap = (const float*)&av;
            const float* bp = (const float*)&bv;
            #pragma unroll
            for (int j = 0; j < 4; ++j)
                #pragma unroll
                for (int i = 0; i < 4; ++i) acc[j][i] += ap[j] * bp[i];
        }
        __syncthreads();
    }

    if (MODE == 0) {
        #pragma unroll
        for (int j = 0; j < 4; ++j) {
            size_t r = r0 + tr * 4 + j;
            float4 v; v.x = acc[j][0]; v.y = acc[j][1]; v.z = acc[j][2]; v.w = acc[j][3];
            *(float4*)&D[r * ldd + c0 + tc * 4] = v;
        }
    } else {
        float* T = smem;                          // 64 x 65
        #pragma unroll
        for (int j = 0; j < 4; ++j)
            #pragma unroll
            for (int i = 0; i < 4; ++i)
                T[(tc * 4 + i) * 65 + tr * 4 + j] = acc[j][i];
        __syncthreads();
        int b  = r0 >> 11, n0l = r0 & (N_ - 1);
        for (int e = t; e < 64 * 64; e += 256) {
            int row = e >> 6, col = e & 63;       // row: o-local, col: n-local
            D[((size_t)b * 512 + c0 + row) * N_ + n0l + col] = T[row * 65 + col];
        }
    }
}

// acto[rn*ostride + ocol0 + o] = relu( max_k dot[b, idx[k], o] + dot[rn, O+o] )
__global__ void k_gather_max(const float* __restrict__ dot, const int* __restrict__ idxg,
                             float* __restrict__ acto, int O, int ostride, int ocol0) {
    int i = blockIdx.x * 256 + threadIdx.x;
    if (i >= B_ * N_ * O) return;
    int o  = i % O;
    int rn = i / O;
    int b  = rn >> 11;
    const int* ip = idxg + (size_t)rn * 4;
    int twoO = O * 2;
    size_t bbase = (size_t)b * N_ * twoO;
    float ctr = dot[(size_t)rn * twoO + O + o];
    float m0 = dot[bbase + (size_t)ip[0] * twoO + o];
    float m1 = dot[bbase + (size_t)ip[1] * twoO + o];
    float m2 = dot[bbase + (size_t)ip[2] * twoO + o];
    float m3 = dot[bbase + (size_t)ip[3] * twoO + o];
    float mx = fmaxf(fmaxf(m0, m1), fmaxf(m2, m3));
    acto[(size_t)rn * ostride + ocol0 + o] = fmaxf(mx + ctr, 0.f);
}

extern "C" void kernel_launch(void* const* d_in, const int* in_sizes, int n_in,
                              void* d_out, int out_size, void* d_ws, size_t ws_size,
                              hipStream_t stream) {
    const float* x  = (const float*)d_in[0];
    const float* W1 = (const float*)d_in[1];
    const float* W2 = (const float*)d_in[2];
    const float* W3 = (const float*)d_in[3];
    const float* W4 = (const float*)d_in[4];
    const float* W5 = (const float*)d_in[5];

    // Compact layout: 12,976,128 floats = 49.5 MiB total (known-good).
    float* ws  = (float*)d_ws;
    float* x1  = ws;                          // 16384*64
    float* x2  = x1 + 1048576;                // 16384*64
    float* x3  = x2 + 1048576;                // 16384*128
    float* x4  = x3 + 2097152;                // 16384*256
    float* dot = x4 + 4194304;                // max 16384*256
    float* xt0 = dot + 4194304;               // 49152
    float* sq  = xt0 + 49152;                 // 16384
    int*   idx = (int*)(sq + 16384);          // 65536 ints
    float* wt  = sq + 16384 + 65536;          // max 512*512
    // knn partials OVERLAY dot (dead during knn; gemm writes dot after merge)
    float* pval = dot;                        // 16384*16 f32
    int*   pidx = (int*)(dot + 262144);       // 16384*16 int

    k_transpose_x<<<64, 256, 0, stream>>>(x, xt0);
    const int knn_grid = B_ * 32 * SEG;       // 1024

    // ---- layer 1: C=3, O=64 ----
    {
        const float* actin = xt0; int C = 3, O = 64, ncols = 2 * O;
        k_sqnorm<<<64, 256, 0, stream>>>(actin, sq, C);
        k_knn_part<3, 4><<<knn_grid, 256, 0, stream>>>(actin, sq, pval, pidx);
        k_knn_merge<<<64, 256, 0, stream>>>(pval, pidx, idx);
        k_pack_w<<<(C * ncols + 255) / 256, 256, 0, stream>>>(W1, wt, O, C, ncols, 2 * C, 0);
        dim3 g((B_ * N_) / 64, ncols / 64);
        k_gemm<0><<<g, 256, 0, stream>>>(actin, C, wt, ncols, dot, ncols, C,
                                         nullptr, nullptr, nullptr, nullptr);
        k_gather_max<<<(B_ * N_ * O + 255) / 256, 256, 0, stream>>>(dot, idx, x1, O, O, 0);
    }
    // ---- layer 2: C=64, O=64 ----
    {
        const float* actin = x1; int C = 64, O = 64, ncols = 2 * O;
        k_sqnorm<<<64, 256, 0, stream>>>(actin, sq, C);
        k_knn_part<64, 64><<<knn_grid, 256, 0, stream>>>(actin, sq, pval, pidx);
        k_knn_merge<<<64, 256, 0, stream>>>(pval, pidx, idx);
        k_pack_w<<<(C * ncols + 255) / 256, 256, 0, stream>>>(W2, wt, O, C, ncols, 2 * C, 0);
        dim3 g((B_ * N_) / 64, ncols / 64);
        k_gemm<0><<<g, 256, 0, stream>>>(actin, C, wt, ncols, dot, ncols, C,
                                         nullptr, nullptr, nullptr, nullptr);
        k_gather_max<<<(B_ * N_ * O + 255) / 256, 256, 0, stream>>>(dot, idx, x2, O, O, 0);
    }
    // ---- layer 3: C=64, O=128 ----
    {
        const float* actin = x2; int C = 64, O = 128, ncols = 2 * O;
        k_sqnorm<<<64, 256, 0, stream>>>(actin, sq, C);
        k_knn_part<64, 64><<<knn_grid, 256, 0, stream>>>(actin, sq, pval, pidx);
        k_knn_merge<<<64, 256, 0, stream>>>(pval, pidx, idx);
        k_pack_w<<<(C * ncols + 255) / 256, 256, 0, stream>>>(W3, wt, O, C, ncols, 2 * C, 0);
        dim3 g((B_ * N_) / 64, ncols / 64);
        k_gemm<0><<<g, 256, 0, stream>>>(actin, C, wt, ncols, dot, ncols, C,
                                         nullptr, nullptr, nullptr, nullptr);
        k_gather_max<<<(B_ * N_ * O + 255) / 256, 256, 0, stream>>>(dot, idx, x3, O, O, 0);
    }
    // ---- layer 4: C=128, O=256 — two 128-output halves so dot <= 16 MB ----
    {
        const float* actin = x3; int C = 128;
        k_sqnorm<<<64, 256, 0, stream>>>(actin, sq, C);
        k_knn_part<128, 128><<<knn_grid, 256, 0, stream>>>(actin, sq, pval, pidx);
        k_knn_merge<<<64, 256, 0, stream>>>(pval, pidx, idx);
        for (int oh = 0; oh < 2; ++oh) {
            int Oh = 128, ncols = 2 * Oh, o0 = oh * 128;
            k_pack_w<<<(C * ncols + 255) / 256, 256, 0, stream>>>(W4, wt, Oh, C, ncols, 2 * C, o0);
            dim3 g((B_ * N_) / 64, ncols / 64);
            k_gemm<0><<<g, 256, 0, stream>>>(actin, C, wt, ncols, dot, ncols, C,
                                             nullptr, nullptr, nullptr, nullptr);
            k_gather_max<<<(B_ * N_ * Oh + 255) / 256, 256, 0, stream>>>(dot, idx, x4, Oh, 256, o0);
        }
    }

    // ---- final: out = W5 * concat(x1,x2,x3,x4), f32 out, (B,512,N) ----
    k_pack_w<<<(512 * 512 + 255) / 256, 256, 0, stream>>>(W5, wt, 512, 512, 512, 512, 0);
    dim3 gf((B_ * N_) / 64, 512 / 64);
    k_gemm<1><<<gf, 256, 0, stream>>>(nullptr, 0, wt, 512, (float*)d_out, 0, 512,
                                      x1, x2, x3, x4);
}

// Round 7
// 718.061 us; speedup vs baseline: 1.3911x; 1.0934x over previous
//
#include <hip/hip_runtime.h>
#include <hip/hip_bf16.h>

#define B_ 8
#define N_ 2048
#define TNK 128
#define TMK 128
#define SEG 8

typedef __bf16 bf16x8 __attribute__((ext_vector_type(8)));
typedef float  f32x4  __attribute__((ext_vector_type(4)));

__global__ void k_transpose_x(const float* __restrict__ x, float* __restrict__ xt) {
    int i = blockIdx.x * 256 + threadIdx.x;
    if (i >= B_ * N_) return;
    int b = i >> 11, n = i & (N_ - 1);
    const float* src = x + (size_t)b * 3 * N_ + n;
    float* dst = xt + (size_t)i * 3;
    dst[0] = src[0];
    dst[1] = src[N_];
    dst[2] = src[2 * N_];
}

__global__ void k_sqnorm(const float* __restrict__ act, float* __restrict__ sq, int C) {
    int i = blockIdx.x * 256 + threadIdx.x;
    if (i >= B_ * N_) return;
    const float* r = act + (size_t)i * C;
    float s = 0.f;
    for (int c = 0; c < C; ++c) s += r[c] * r[c];
    sq[i] = s;
}

__global__ void k_pack_w(const float* __restrict__ W, float* __restrict__ Wt,
                         int O, int C, int ncols, int wrow, int orow0) {
    int i = blockIdx.x * 256 + threadIdx.x;
    if (i >= C * ncols) return;
    int k = i / ncols, o2 = i % ncols;
    int o   = ((o2 < O) ? o2 : o2 - O) + orow0;
    int col = (o2 < O) ? k : (C + k);
    Wt[i] = W[(size_t)o * wrow + col];
}

__device__ __forceinline__ void ins4(float& v0, float& v1, float& v2, float& v3,
                                     int& i0, int& i1, int& i2, int& i3,
                                     float p, int m) {
    bool g3 = p > v3, g2 = p > v2, g1 = p > v1, g0 = p > v0;
    v3 = g2 ? v2 : (g3 ? p : v3); i3 = g2 ? i2 : (g3 ? m : i3);
    v2 = g1 ? v1 : (g2 ? p : v2); i2 = g1 ? i1 : (g2 ? m : i2);
    v1 = g0 ? v0 : (g1 ? p : v1); i1 = g0 ? i0 : (g1 ? m : i1);
    v0 = g0 ? p  : v0;            i0 = g0 ? m  : i0;
}

// Segmented pairwise-distance + per-segment top-4.
// Round-6 fix: 8x8 micro-tile (was 4x8) -> FMA:ds_read ratio 2.67->4.0.
// Tile 128n x 128m, 256 threads (16 tr-groups x 16 lanes); thread owns rows
// tr*8..tr*8+7 and m = i*16+tcl (i=0..7). Candidate order per (row,m) is
// identical to prior rounds (same i*16+lane mapping, seg-ascending merge).
template<int C, int CP>
__global__ __launch_bounds__(256) void k_knn_part(
    const float* __restrict__ act, const float* __restrict__ sqg,
    float* __restrict__ pval, int* __restrict__ pidx)
{
    constexpr int CHUNK = (CP < 32) ? CP : 32;
    constexpr int NCH   = CP / CHUNK;
    constexpr int S     = CHUNK + 4;
    __shared__ float xn[TNK * S];
    __shared__ float xm[TMK * S];
    __shared__ float sqn[TNK];
    __shared__ float sqm[TMK];

    const int seg = blockIdx.x & (SEG - 1);
    const int nb  = (blockIdx.x >> 3) & 15;   // N_/TNK = 16 n-blocks
    const int b   = blockIdx.x >> 7;          // / (SEG*16)
    const int n0  = nb * TNK;
    const int t   = threadIdx.x;
    const int tr  = t >> 4;
    const int tcl = t & 15;
    const float* ab = act + (size_t)b * N_ * C;
    constexpr int C4N = CHUNK >> 2;

    float tv[8][4];
    int   ti[8][4];
    #pragma unroll
    for (int j = 0; j < 8; ++j)
        #pragma unroll
        for (int q = 0; q < 4; ++q) { tv[j][q] = -3.4e38f; ti[j][q] = 0; }

    const int mend = (seg + 1) * (N_ / SEG);
    for (int m0 = seg * (N_ / SEG); m0 < mend; m0 += TMK) {
        float acc[8][8];
        #pragma unroll
        for (int j = 0; j < 8; ++j)
            #pragma unroll
            for (int i = 0; i < 8; ++i) acc[j][i] = 0.f;

        for (int ch = 0; ch < NCH; ++ch) {
            const int cbase = ch * CHUNK;
            __syncthreads();   // protects xn/xm/sq reuse across chunks/m0
            for (int e = t; e < TNK * C4N; e += 256) {
                int r = e / C4N, c4 = (e % C4N) << 2;
                const float* src = ab + (size_t)(n0 + r) * C + cbase + c4;
                float4 v;
                if constexpr (CP == C) {
                    v = *(const float4*)src;
                } else {
                    v.x = (cbase + c4 + 0 < C) ? src[0] : 0.f;
                    v.y = (cbase + c4 + 1 < C) ? src[1] : 0.f;
                    v.z = (cbase + c4 + 2 < C) ? src[2] : 0.f;
                    v.w = (cbase + c4 + 3 < C) ? src[3] : 0.f;
                }
                *(float4*)&xn[r * S + c4] = v;
            }
            for (int e = t; e < TMK * C4N; e += 256) {
                int r = e / C4N, c4 = (e % C4N) << 2;
                const float* src = ab + (size_t)(m0 + r) * C + cbase + c4;
                float4 v;
                if constexpr (CP == C) {
                    v = *(const float4*)src;
                } else {
                    v.x = (cbase + c4 + 0 < C) ? src[0] : 0.f;
                    v.y = (cbase + c4 + 1 < C) ? src[1] : 0.f;
                    v.z = (cbase + c4 + 2 < C) ? src[2] : 0.f;
                    v.w = (cbase + c4 + 3 < C) ? src[3] : 0.f;
                }
                *(float4*)&xm[r * S + c4] = v;
            }
            if (ch == 0) {
                if (t < TNK) sqn[t] = sqg[b * N_ + n0 + t];
                if (t < TMK) sqm[t] = sqg[b * N_ + m0 + t];
            }
            __syncthreads();

            for (int c4 = 0; c4 < CHUNK; c4 += 4) {
                float4 a[8], bb[8];
                #pragma unroll
                for (int j = 0; j < 8; ++j) a[j] = *(float4*)&xn[(tr * 8 + j) * S + c4];
                #pragma unroll
                for (int i = 0; i < 8; ++i) bb[i] = *(float4*)&xm[(i * 16 + tcl) * S + c4];
                #pragma unroll
                for (int j = 0; j < 8; ++j)
                    #pragma unroll
                    for (int i = 0; i < 8; ++i)
                        acc[j][i] += a[j].x * bb[i].x + a[j].y * bb[i].y
                                   + a[j].z * bb[i].z + a[j].w * bb[i].w;
            }
        }

        #pragma unroll
        for (int i = 0; i < 8; ++i) {
            int   m  = m0 + i * 16 + tcl;
            float sm = sqm[i * 16 + tcl];
            #pragma unroll
            for (int j = 0; j < 8; ++j) {
                float pd = 2.f * acc[j][i] - sqn[tr * 8 + j] - sm;
                ins4(tv[j][0], tv[j][1], tv[j][2], tv[j][3],
                     ti[j][0], ti[j][1], ti[j][2], ti[j][3], pd, m);
            }
        }
    }

    // butterfly merge across the 16 lanes of each tr-group
    #pragma unroll
    for (int j = 0; j < 8; ++j) {
        float v0 = tv[j][0], v1 = tv[j][1], v2 = tv[j][2], v3 = tv[j][3];
        int   i0 = ti[j][0], i1 = ti[j][1], i2 = ti[j][2], i3 = ti[j][3];
        #pragma unroll
        for (int st = 1; st < 16; st <<= 1) {
            float w0 = __shfl_xor(v0, st), w1 = __shfl_xor(v1, st);
            float w2 = __shfl_xor(v2, st), w3 = __shfl_xor(v3, st);
            int   j0 = __shfl_xor(i0, st), j1 = __shfl_xor(i1, st);
            int   j2 = __shfl_xor(i2, st), j3 = __shfl_xor(i3, st);
            ins4(v0, v1, v2, v3, i0, i1, i2, i3, w0, j0);
            ins4(v0, v1, v2, v3, i0, i1, i2, i3, w1, j1);
            ins4(v0, v1, v2, v3, i0, i1, i2, i3, w2, j2);
            ins4(v0, v1, v2, v3, i0, i1, i2, i3, w3, j3);
        }
        if (tcl == 0) {
            size_t base = ((size_t)b * N_ + n0 + tr * 8 + j) * (SEG * 4) + seg * 4;
            pval[base + 0] = v0; pval[base + 1] = v1;
            pval[base + 2] = v2; pval[base + 3] = v3;
            pidx[base + 0] = i0; pidx[base + 1] = i1;
            pidx[base + 2] = i2; pidx[base + 3] = i3;
        }
    }
}

__global__ void k_knn_merge(const float* __restrict__ pval, const int* __restrict__ pidx,
                            int* __restrict__ idxo) {
    int rn = blockIdx.x * 256 + threadIdx.x;
    if (rn >= B_ * N_) return;
    const float* pv = pval + (size_t)rn * (SEG * 4);
    const int*   pi = pidx + (size_t)rn * (SEG * 4);
    float v0 = pv[0], v1 = pv[1], v2 = pv[2], v3 = pv[3];
    int   i0 = pi[0], i1 = pi[1], i2 = pi[2], i3 = pi[3];
    for (int s = 1; s < SEG; ++s)
        #pragma unroll
        for (int q = 0; q < 4; ++q)
            ins4(v0, v1, v2, v3, i0, i1, i2, i3, pv[s * 4 + q], pi[s * 4 + q]);
    int* op = idxo + (size_t)rn * 4;
    op[0] = i0; op[1] = i1; op[2] = i2; op[3] = i3;
}

// Tiled f32 GEMM (conv layers only): D(R x ncols) = A(R x K) * Bt(K x ncols).
__global__ __launch_bounds__(256) void k_gemm(
    const float* __restrict__ A, int lda,
    const float* __restrict__ Bt, int ldb,
    float* __restrict__ D, int ldd, int K)
{
    __shared__ float At[32 * 68];
    __shared__ float Bs[32 * 68];
    const int r0 = blockIdx.x * 64;
    const int c0 = blockIdx.y * 64;
    const int t  = threadIdx.x;
    const int tr = t >> 4, tc = t & 15;
    float acc[4][4];
    #pragma unroll
    for (int j = 0; j < 4; ++j)
        #pragma unroll
        for (int i = 0; i < 4; ++i) acc[j][i] = 0.f;

    for (int k0 = 0; k0 < K; k0 += 32) {
        for (int e = t; e < 64 * 32; e += 256) {
            int r = e >> 5, kk = e & 31;
            int kg = k0 + kk;
            float v = (kg < K) ? A[(size_t)(r0 + r) * lda + kg] : 0.f;
            At[kk * 68 + r] = v;
        }
        for (int e = t; e < 32 * 16; e += 256) {
            int kk = e >> 4, c4 = (e & 15) << 2;
            int kg = k0 + kk;
            float4 v = {0.f, 0.f, 0.f, 0.f};
            if (kg < K) v = *(const float4*)&Bt[(size_t)kg * ldb + c0 + c4];
            *(float4*)&Bs[kk * 68 + c4] = v;
        }
        __syncthreads();
        for (int kk = 0; kk < 32; ++kk) {
            float4 av = *(float4*)&At[kk * 68 + tr * 4];
            float4 bv = *(float4*)&Bs[kk * 68 + tc * 4];
            const float* ap = (const float*)&av;
            const float* bp = (const float*)&bv;
            #pragma unroll
            for (int j = 0; j < 4; ++j)
                #pragma unroll
                for (int i = 0; i < 4; ++i) acc[j][i] += ap[j] * bp[i];
        }
        __syncthreads();
    }

    #pragma unroll
    for (int j = 0; j < 4; ++j) {
        size_t r = r0 + tr * 4 + j;
        float4 v; v.x = acc[j][0]; v.y = acc[j][1]; v.z = acc[j][2]; v.w = acc[j][3];
        *(float4*)&D[r * ldd + c0 + tc * 4] = v;
    }
}

__global__ void k_gather_max(const float* __restrict__ dot, const int* __restrict__ idxg,
                             float* __restrict__ acto, int O, int ostride, int ocol0) {
    int i = blockIdx.x * 256 + threadIdx.x;
    if (i >= B_ * N_ * O) return;
    int o  = i % O;
    int rn = i / O;
    int b  = rn >> 11;
    const int* ip = idxg + (size_t)rn * 4;
    int twoO = O * 2;
    size_t bbase = (size_t)b * N_ * twoO;
    float ctr = dot[(size_t)rn * twoO + O + o];
    float m0 = dot[bbase + (size_t)ip[0] * twoO + o];
    float m1 = dot[bbase + (size_t)ip[1] * twoO + o];
    float m2 = dot[bbase + (size_t)ip[2] * twoO + o];
    float m3 = dot[bbase + (size_t)ip[3] * twoO + o];
    float mx = fmaxf(fmaxf(m0, m1), fmaxf(m2, m3));
    acto[(size_t)rn * ostride + ocol0 + o] = fmaxf(mx + ctr, 0.f);
}

__device__ __forceinline__ unsigned short f2bf(float f) {
    __hip_bfloat16 h = __float2bfloat16(f);
    return *reinterpret_cast<unsigned short*>(&h);
}

// featb[bn][c] (bf16, c-contig 512) from x1|x2|x3|x4 concat; 8 elems/thread.
__global__ void k_feat_bf16(const float* __restrict__ x1, const float* __restrict__ x2,
                            const float* __restrict__ x3, const float* __restrict__ x4,
                            unsigned short* __restrict__ fb) {
    int i = blockIdx.x * 256 + threadIdx.x;
    if (i >= B_ * N_ * 512 / 8) return;
    int rn = i >> 6, c8 = (i & 63) << 3;
    const float* src;
    if      (c8 < 64)  src = x1 + (size_t)rn * 64  + c8;
    else if (c8 < 128) src = x2 + (size_t)rn * 64  + (c8 - 64);
    else if (c8 < 256) src = x3 + (size_t)rn * 128 + (c8 - 128);
    else               src = x4 + (size_t)rn * 256 + (c8 - 256);
    float4 va = *(const float4*)src;
    float4 vb = *(const float4*)(src + 4);
    uint4 u;
    u.x = ((unsigned)f2bf(va.y) << 16) | f2bf(va.x);
    u.y = ((unsigned)f2bf(va.w) << 16) | f2bf(va.z);
    u.z = ((unsigned)f2bf(vb.y) << 16) | f2bf(vb.x);
    u.w = ((unsigned)f2bf(vb.w) << 16) | f2bf(vb.z);
    *(uint4*)&fb[(size_t)i * 8] = u;
}

__global__ void k_w5_bf16(const float* __restrict__ W5, unsigned short* __restrict__ wb) {
    int i = blockIdx.x * 256 + threadIdx.x;
    if (i >= 512 * 512 / 8) return;
    const float* src = W5 + (size_t)i * 8;
    float4 va = *(const float4*)src;
    float4 vb = *(const float4*)(src + 4);
    uint4 u;
    u.x = ((unsigned)f2bf(va.y) << 16) | f2bf(va.x);
    u.y = ((unsigned)f2bf(va.w) << 16) | f2bf(va.z);
    u.z = ((unsigned)f2bf(vb.y) << 16) | f2bf(vb.x);
    u.w = ((unsigned)f2bf(vb.w) << 16) | f2bf(vb.z);
    *(uint4*)&wb[(size_t)i * 8] = u;
}

// MFMA bf16 final GEMM: out[o][bn] = sum_c W5[o][c]*feat[bn][c], f32 out to
// (B,512,N). A=w5b (M=512), B=featb (N=16384), K=512. 128x128 block, 4 waves
// 2x2, each wave 64x64 via 4x4 frags of mfma_f32_16x16x32_bf16.
// Layout (m89-verified): D col=lane&15, row=(lane>>4)*4+reg; A/B lane&15 =
// row/col, k = (lane>>4)*8 + elem.
__global__ __launch_bounds__(256) void k_mfma_final(
    const unsigned short* __restrict__ Ab, const unsigned short* __restrict__ Bb,
    float* __restrict__ out)
{
    __shared__ unsigned short As[128 * 40];   // [row o][k] pad 32->40
    __shared__ unsigned short Bs[128 * 40];   // [row bn][k]
    const int bn0 = blockIdx.x * 128;
    const int o0  = blockIdx.y * 128;
    const int t    = threadIdx.x;
    const int w    = t >> 6;
    const int lane = t & 63;
    const int wm = w >> 1, wn = w & 1;
    const int l15 = lane & 15, l4 = lane >> 4;

    f32x4 acc[4][4];
    #pragma unroll
    for (int mi = 0; mi < 4; ++mi)
        #pragma unroll
        for (int ni = 0; ni < 4; ++ni) acc[mi][ni] = (f32x4){0.f, 0.f, 0.f, 0.f};

    for (int k0 = 0; k0 < 512; k0 += 32) {
        __syncthreads();
        for (int e = t; e < 128 * 4; e += 256) {
            int row = e >> 2, q = e & 3;
            *(float4*)&As[row * 40 + q * 8] =
                *(const float4*)&Ab[(size_t)(o0 + row) * 512 + k0 + q * 8];
            *(float4*)&Bs[row * 40 + q * 8] =
                *(const float4*)&Bb[(size_t)(bn0 + row) * 512 + k0 + q * 8];
        }
        __syncthreads();
        bf16x8 af[4], bf[4];
        #pragma unroll
        for (int mi = 0; mi < 4; ++mi)
            af[mi] = *(const bf16x8*)&As[(wm * 64 + mi * 16 + l15) * 40 + l4 * 8];
        #pragma unroll
        for (int ni = 0; ni < 4; ++ni)
            bf[ni] = *(const bf16x8*)&Bs[(wn * 64 + ni * 16 + l15) * 40 + l4 * 8];
        #pragma unroll
        for (int mi = 0; mi < 4; ++mi)
            #pragma unroll
            for (int ni = 0; ni < 4; ++ni)
                acc[mi][ni] = __builtin_amdgcn_mfma_f32_16x16x32_bf16(
                    af[mi], bf[ni], acc[mi][ni], 0, 0, 0);
    }

    const int bidx = bn0 >> 11;               // batch (128 | 2048, no straddle)
    const int nloc = bn0 & (N_ - 1);
    #pragma unroll
    for (int mi = 0; mi < 4; ++mi) {
        #pragma unroll
        for (int ni = 0; ni < 4; ++ni) {
            int o = o0 + wm * 64 + mi * 16 + l4 * 4;
            int n = nloc + wn * 64 + ni * 16 + l15;
            #pragma unroll
            for (int r = 0; r < 4; ++r)
                out[((size_t)bidx * 512 + o + r) * N_ + n] = acc[mi][ni][r];
        }
    }
}

extern "C" void kernel_launch(void* const* d_in, const int* in_sizes, int n_in,
                              void* d_out, int out_size, void* d_ws, size_t ws_size,
                              hipStream_t stream) {
    const float* x  = (const float*)d_in[0];
    const float* W1 = (const float*)d_in[1];
    const float* W2 = (const float*)d_in[2];
    const float* W3 = (const float*)d_in[3];
    const float* W4 = (const float*)d_in[4];
    const float* W5 = (const float*)d_in[5];

    // 49.5 MiB layout (known-good).
    float* ws  = (float*)d_ws;
    float* x1  = ws;                          // 16384*64
    float* x2  = x1 + 1048576;                // 16384*64
    float* x3  = x2 + 1048576;                // 16384*128
    float* x4  = x3 + 2097152;                // 16384*256
    float* dot = x4 + 4194304;                // max 16384*256
    float* xt0 = dot + 4194304;               // 49152
    float* sq  = xt0 + 49152;                 // 16384
    int*   idx = (int*)(sq + 16384);          // 65536 ints
    float* wt  = sq + 16384 + 65536;          // max 256*512
    // overlays (stream-ordered, regions dead at use time):
    float* pval = dot;                        // 16384*32 f32
    int*   pidx = (int*)(dot + 524288);       // 16384*32 int
    unsigned short* featb = (unsigned short*)dot;   // 16384*512 bf16 = 16MB
    unsigned short* w5b   = (unsigned short*)xt0;   // 512*512 bf16 over xt0/sq/idx

    k_transpose_x<<<64, 256, 0, stream>>>(x, xt0);
    const int knn_grid = B_ * 16 * SEG;       // 1024

    // ---- layer 1: C=3, O=64 ----
    {
        const float* actin = xt0; int C = 3, O = 64, ncols = 2 * O;
        k_sqnorm<<<64, 256, 0, stream>>>(actin, sq, C);
        k_knn_part<3, 4><<<knn_grid, 256, 0, stream>>>(actin, sq, pval, pidx);
        k_knn_merge<<<64, 256, 0, stream>>>(pval, pidx, idx);
        k_pack_w<<<(C * ncols + 255) / 256, 256, 0, stream>>>(W1, wt, O, C, ncols, 2 * C, 0);
        dim3 g((B_ * N_) / 64, ncols / 64);
        k_gemm<<<g, 256, 0, stream>>>(actin, C, wt, ncols, dot, ncols, C);
        k_gather_max<<<(B_ * N_ * O + 255) / 256, 256, 0, stream>>>(dot, idx, x1, O, O, 0);
    }
    // ---- layer 2: C=64, O=64 ----
    {
        const float* actin = x1; int C = 64, O = 64, ncols = 2 * O;
        k_sqnorm<<<64, 256, 0, stream>>>(actin, sq, C);
        k_knn_part<64, 64><<<knn_grid, 256, 0, stream>>>(actin, sq, pval, pidx);
        k_knn_merge<<<64, 256, 0, stream>>>(pval, pidx, idx);
        k_pack_w<<<(C * ncols + 255) / 256, 256, 0, stream>>>(W2, wt, O, C, ncols, 2 * C, 0);
        dim3 g((B_ * N_) / 64, ncols / 64);
        k_gemm<<<g, 256, 0, stream>>>(actin, C, wt, ncols, dot, ncols, C);
        k_gather_max<<<(B_ * N_ * O + 255) / 256, 256, 0, stream>>>(dot, idx, x2, O, O, 0);
    }
    // ---- layer 3: C=64, O=128 ----
    {
        const float* actin = x2; int C = 64, O = 128, ncols = 2 * O;
        k_sqnorm<<<64, 256, 0, stream>>>(actin, sq, C);
        k_knn_part<64, 64><<<knn_grid, 256, 0, stream>>>(actin, sq, pval, pidx);
        k_knn_merge<<<64, 256, 0, stream>>>(pval, pidx, idx);
        k_pack_w<<<(C * ncols + 255) / 256, 256, 0, stream>>>(W3, wt, O, C, ncols, 2 * C, 0);
        dim3 g((B_ * N_) / 64, ncols / 64);
        k_gemm<<<g, 256, 0, stream>>>(actin, C, wt, ncols, dot, ncols, C);
        k_gather_max<<<(B_ * N_ * O + 255) / 256, 256, 0, stream>>>(dot, idx, x3, O, O, 0);
    }
    // ---- layer 4: C=128, O=256 — two 128-output halves so dot <= 16 MB ----
    {
        const float* actin = x3; int C = 128;
        k_sqnorm<<<64, 256, 0, stream>>>(actin, sq, C);
        k_knn_part<128, 128><<<knn_grid, 256, 0, stream>>>(actin, sq, pval, pidx);
        k_knn_merge<<<64, 256, 0, stream>>>(pval, pidx, idx);
        for (int oh = 0; oh < 2; ++oh) {
            int Oh = 128, ncols = 2 * Oh, o0 = oh * 128;
            k_pack_w<<<(C * ncols + 255) / 256, 256, 0, stream>>>(W4, wt, Oh, C, ncols, 2 * C, o0);
            dim3 g((B_ * N_) / 64, ncols / 64);
            k_gemm<<<g, 256, 0, stream>>>(actin, C, wt, ncols, dot, ncols, C);
            k_gather_max<<<(B_ * N_ * Oh + 255) / 256, 256, 0, stream>>>(dot, idx, x4, Oh, 256, o0);
        }
    }

    // ---- final: out = W5 * concat(x1..x4) via bf16 MFMA, f32 out (B,512,N) ----
    k_feat_bf16<<<(B_ * N_ * 512 / 8 + 255) / 256, 256, 0, stream>>>(x1, x2, x3, x4, featb);
    k_w5_bf16<<<(512 * 512 / 8 + 255) / 256, 256, 0, stream>>>(W5, w5b);
    dim3 gm(B_ * N_ / 128, 512 / 128);
    k_mfma_final<<<gm, 256, 0, stream>>>(w5b, featb, (float*)d_out);
}

// Round 8
// 536.793 us; speedup vs baseline: 1.8608x; 1.3377x over previous
//
#include <hip/hip_runtime.h>
#include <hip/hip_bf16.h>

#define B_ 8
#define N_ 2048
#define SEG 8
#define TMM 64    // m-rows per tile-iter
#define TNN 128   // n-cols per block

typedef __bf16 bf16x8 __attribute__((ext_vector_type(8)));
typedef float  f32x4  __attribute__((ext_vector_type(4)));
typedef unsigned short u16;

__device__ __forceinline__ u16 f2bf(float f) {
    __hip_bfloat16 h = __float2bfloat16(f);
    return *reinterpret_cast<u16*>(&h);
}
__device__ __forceinline__ float bf2f(u16 u) {
    unsigned v = ((unsigned)u) << 16;
    return *reinterpret_cast<float*>(&v);
}

__global__ void k_transpose_x(const float* __restrict__ x, float* __restrict__ xt) {
    int i = blockIdx.x * 256 + threadIdx.x;
    if (i >= B_ * N_) return;
    int b = i >> 11, n = i & (N_ - 1);
    const float* src = x + (size_t)b * 3 * N_ + n;
    float* dst = xt + (size_t)i * 3;
    dst[0] = src[0];
    dst[1] = src[N_];
    dst[2] = src[2 * N_];
}

__global__ void k_sqnorm(const float* __restrict__ act, float* __restrict__ sq, int C) {
    int i = blockIdx.x * 256 + threadIdx.x;
    if (i >= B_ * N_) return;
    const float* r = act + (size_t)i * C;
    float s = 0.f;
    for (int c = 0; c < C; ++c) s += r[c] * r[c];
    sq[i] = s;
}

// 3-term bf16 split: x = hi + mid + lo (exact residuals, RNE). Pad k>=C with 0.
template<int C, int CP>
__global__ void k_split3(const float* __restrict__ act, u16* __restrict__ xh,
                         u16* __restrict__ xm, u16* __restrict__ xl) {
    int i = blockIdx.x * 256 + threadIdx.x;
    if (i >= B_ * N_ * CP / 8) return;
    int rn = i / (CP / 8), c8 = (i % (CP / 8)) * 8;
    u16 h[8], m[8], l[8];
    #pragma unroll
    for (int j = 0; j < 8; ++j) {
        int c = c8 + j;
        float x = (c < C) ? act[(size_t)rn * C + c] : 0.f;
        u16 hh = f2bf(x);
        float r1 = x - bf2f(hh);
        u16 mm = f2bf(r1);
        float r2 = r1 - bf2f(mm);
        h[j] = hh; m[j] = mm; l[j] = f2bf(r2);
    }
    *(uint4*)&xh[(size_t)i * 8] = *(uint4*)h;
    *(uint4*)&xm[(size_t)i * 8] = *(uint4*)m;
    *(uint4*)&xl[(size_t)i * 8] = *(uint4*)l;
}

__global__ void k_pack_w(const float* __restrict__ W, float* __restrict__ Wt,
                         int O, int C, int ncols, int wrow, int orow0) {
    int i = blockIdx.x * 256 + threadIdx.x;
    if (i >= C * ncols) return;
    int k = i / ncols, o2 = i % ncols;
    int o   = ((o2 < O) ? o2 : o2 - O) + orow0;
    int col = (o2 < O) ? k : (C + k);
    Wt[i] = W[(size_t)o * wrow + col];
}

__device__ __forceinline__ void ins4(float& v0, float& v1, float& v2, float& v3,
                                     int& i0, int& i1, int& i2, int& i3,
                                     float p, int m) {
    bool g3 = p > v3, g2 = p > v2, g1 = p > v1, g0 = p > v0;
    v3 = g2 ? v2 : (g3 ? p : v3); i3 = g2 ? i2 : (g3 ? m : i3);
    v2 = g1 ? v1 : (g2 ? p : v2); i2 = g1 ? i1 : (g2 ? m : i2);
    v1 = g0 ? v0 : (g1 ? p : v1); i1 = g0 ? i0 : (g1 ? m : i1);
    v0 = g0 ? p  : v0;            i0 = g0 ? m  : i0;
}

// knn via 3-term-split MFMA (6 products: hh,hm,mh,mm,hl,lh -> ~1e-7 rel error,
// tighter than the f32 FMA chain it replaces). score = 2*inner - sqm; the
// -sqn[n] per-column constant is rank-invariant and dropped.
// Block: 4 waves (2wm x 2wn); tile TMM=64 m-rows x TNN=128 n-cols; wave =
// 32m x 64n of 16x16x32 frags. Fragment addressing cloned from verified
// k_mfma_final (A row uses l15, k uses l4*8; D row=l4*4+reg (m), col=l15 (n)).
template<int CP>
__global__ __launch_bounds__(256) void k_knn_mfma(
    const u16* __restrict__ xh, const u16* __restrict__ xmd, const u16* __restrict__ xl,
    const float* __restrict__ sqg, float* __restrict__ pval, int* __restrict__ pidx)
{
    __shared__ __align__(16) u16 sm[3 * TNN * 40 + 3 * TMM * 40];
    __shared__ float sqm_l[TMM];
    u16* Anh = sm;
    u16* Anm = sm + TNN * 40;
    u16* Anl = sm + 2 * TNN * 40;
    u16* Amh = sm + 3 * TNN * 40;
    u16* Amm = Amh + TMM * 40;
    u16* Aml = Amh + 2 * TMM * 40;

    const int bid = blockIdx.x;
    const int seg = bid & (SEG - 1);
    const int nb  = (bid >> 3) & 15;
    const int b   = bid >> 7;
    const int n0  = nb * TNN;
    const int t    = threadIdx.x;
    const int w    = t >> 6, lane = t & 63;
    const int wm = w >> 1, wn = w & 1;
    const int l15 = lane & 15, l4 = lane >> 4;
    const size_t rowbase = (size_t)b * N_;

    float tv[4][4];
    int   ti[4][4];
    #pragma unroll
    for (int ni = 0; ni < 4; ++ni)
        #pragma unroll
        for (int q = 0; q < 4; ++q) { tv[ni][q] = -3.4e38f; ti[ni][q] = 0; }

    const int mstart = seg * (N_ / SEG);
    for (int m0 = mstart; m0 < mstart + N_ / SEG; m0 += TMM) {
        f32x4 acc[2][4];
        #pragma unroll
        for (int mi = 0; mi < 2; ++mi)
            #pragma unroll
            for (int ni = 0; ni < 4; ++ni) acc[mi][ni] = (f32x4){0.f, 0.f, 0.f, 0.f};

        for (int k0 = 0; k0 < CP; k0 += 32) {
            __syncthreads();
            for (int e = t; e < TNN * 4; e += 256) {
                int row = e >> 2, q = e & 3;
                size_t g = (rowbase + n0 + row) * CP + k0 + q * 8;
                int d = row * 40 + q * 8;
                *(uint4*)&Anh[d] = *(const uint4*)&xh[g];
                *(uint4*)&Anm[d] = *(const uint4*)&xmd[g];
                *(uint4*)&Anl[d] = *(const uint4*)&xl[g];
            }
            {   // TMM*4 == 256: one per thread
                int row = t >> 2, q = t & 3;
                size_t g = (rowbase + m0 + row) * CP + k0 + q * 8;
                int d = row * 40 + q * 8;
                *(uint4*)&Amh[d] = *(const uint4*)&xh[g];
                *(uint4*)&Amm[d] = *(const uint4*)&xmd[g];
                *(uint4*)&Aml[d] = *(const uint4*)&xl[g];
            }
            if (k0 == 0 && t < TMM) sqm_l[t] = sqg[rowbase + m0 + t];
            __syncthreads();

            bf16x8 amh[2], amm[2], aml[2], bnh[4], bnm[4], bnl[4];
            #pragma unroll
            for (int mi = 0; mi < 2; ++mi) {
                int off = (wm * 32 + mi * 16 + l15) * 40 + l4 * 8;
                amh[mi] = *(const bf16x8*)&Amh[off];
                amm[mi] = *(const bf16x8*)&Amm[off];
                aml[mi] = *(const bf16x8*)&Aml[off];
            }
            #pragma unroll
            for (int ni = 0; ni < 4; ++ni) {
                int off = (wn * 64 + ni * 16 + l15) * 40 + l4 * 8;
                bnh[ni] = *(const bf16x8*)&Anh[off];
                bnm[ni] = *(const bf16x8*)&Anm[off];
                bnl[ni] = *(const bf16x8*)&Anl[off];
            }
            #pragma unroll
            for (int mi = 0; mi < 2; ++mi)
                #pragma unroll
                for (int ni = 0; ni < 4; ++ni) {
                    f32x4 a = acc[mi][ni];
                    a = __builtin_amdgcn_mfma_f32_16x16x32_bf16(amh[mi], bnh[ni], a, 0, 0, 0);
                    a = __builtin_amdgcn_mfma_f32_16x16x32_bf16(amh[mi], bnm[ni], a, 0, 0, 0);
                    a = __builtin_amdgcn_mfma_f32_16x16x32_bf16(amm[mi], bnh[ni], a, 0, 0, 0);
                    a = __builtin_amdgcn_mfma_f32_16x16x32_bf16(amm[mi], bnm[ni], a, 0, 0, 0);
                    a = __builtin_amdgcn_mfma_f32_16x16x32_bf16(amh[mi], bnl[ni], a, 0, 0, 0);
                    a = __builtin_amdgcn_mfma_f32_16x16x32_bf16(aml[mi], bnh[ni], a, 0, 0, 0);
                    acc[mi][ni] = a;
                }
        }
        #pragma unroll
        for (int ni = 0; ni < 4; ++ni)
            #pragma unroll
            for (int mi = 0; mi < 2; ++mi)
                #pragma unroll
                for (int r = 0; r < 4; ++r) {
                    int mloc = wm * 32 + mi * 16 + l4 * 4 + r;
                    float sc = 2.f * acc[mi][ni][r] - sqm_l[mloc];
                    ins4(tv[ni][0], tv[ni][1], tv[ni][2], tv[ni][3],
                         ti[ni][0], ti[ni][1], ti[ni][2], ti[ni][3], sc, m0 + mloc);
                }
    }

    __syncthreads();
    float* sv = (float*)sm;            // [2][128][4] val
    int*   si = (int*)sm + 1024;       // [2][128][4] idx
    #pragma unroll
    for (int ni = 0; ni < 4; ++ni) {
        float v0 = tv[ni][0], v1 = tv[ni][1], v2 = tv[ni][2], v3 = tv[ni][3];
        int   i0 = ti[ni][0], i1 = ti[ni][1], i2 = ti[ni][2], i3 = ti[ni][3];
        #pragma unroll
        for (int st = 16; st < 64; st <<= 1) {
            float w0 = __shfl_xor(v0, st), w1 = __shfl_xor(v1, st);
            float w2 = __shfl_xor(v2, st), w3 = __shfl_xor(v3, st);
            int   j0 = __shfl_xor(i0, st), j1 = __shfl_xor(i1, st);
            int   j2 = __shfl_xor(i2, st), j3 = __shfl_xor(i3, st);
            ins4(v0, v1, v2, v3, i0, i1, i2, i3, w0, j0);
            ins4(v0, v1, v2, v3, i0, i1, i2, i3, w1, j1);
            ins4(v0, v1, v2, v3, i0, i1, i2, i3, w2, j2);
            ins4(v0, v1, v2, v3, i0, i1, i2, i3, w3, j3);
        }
        if (l4 == 0) {
            int col = wn * 64 + ni * 16 + l15;
            int base = (wm * 128 + col) * 4;
            sv[base + 0] = v0; sv[base + 1] = v1; sv[base + 2] = v2; sv[base + 3] = v3;
            si[base + 0] = i0; si[base + 1] = i1; si[base + 2] = i2; si[base + 3] = i3;
        }
    }
    __syncthreads();
    if (t < 128) {
        int b0 = t * 4, b1 = (128 + t) * 4;
        float v0 = sv[b0], v1 = sv[b0 + 1], v2 = sv[b0 + 2], v3 = sv[b0 + 3];
        int   i0 = si[b0], i1 = si[b0 + 1], i2 = si[b0 + 2], i3 = si[b0 + 3];
        #pragma unroll
        for (int q = 0; q < 4; ++q)
            ins4(v0, v1, v2, v3, i0, i1, i2, i3, sv[b1 + q], si[b1 + q]);
        size_t pb = (rowbase + n0 + t) * (SEG * 4) + seg * 4;
        pval[pb + 0] = v0; pval[pb + 1] = v1; pval[pb + 2] = v2; pval[pb + 3] = v3;
        pidx[pb + 0] = i0; pidx[pb + 1] = i1; pidx[pb + 2] = i2; pidx[pb + 3] = i3;
    }
}

__global__ void k_knn_merge(const float* __restrict__ pval, const int* __restrict__ pidx,
                            int* __restrict__ idxo) {
    int rn = blockIdx.x * 256 + threadIdx.x;
    if (rn >= B_ * N_) return;
    const float* pv = pval + (size_t)rn * (SEG * 4);
    const int*   pi = pidx + (size_t)rn * (SEG * 4);
    float v0 = pv[0], v1 = pv[1], v2 = pv[2], v3 = pv[3];
    int   i0 = pi[0], i1 = pi[1], i2 = pi[2], i3 = pi[3];
    for (int s = 1; s < SEG; ++s)
        #pragma unroll
        for (int q = 0; q < 4; ++q)
            ins4(v0, v1, v2, v3, i0, i1, i2, i3, pv[s * 4 + q], pi[s * 4 + q]);
    int* op = idxo + (size_t)rn * 4;
    op[0] = i0; op[1] = i1; op[2] = i2; op[3] = i3;
}

__global__ __launch_bounds__(256) void k_gemm(
    const float* __restrict__ A, int lda,
    const float* __restrict__ Bt, int ldb,
    float* __restrict__ D, int ldd, int K)
{
    __shared__ float At[32 * 68];
    __shared__ float Bs[32 * 68];
    const int r0 = blockIdx.x * 64;
    const int c0 = blockIdx.y * 64;
    const int t  = threadIdx.x;
    const int tr = t >> 4, tc = t & 15;
    float acc[4][4];
    #pragma unroll
    for (int j = 0; j < 4; ++j)
        #pragma unroll
        for (int i = 0; i < 4; ++i) acc[j][i] = 0.f;

    for (int k0 = 0; k0 < K; k0 += 32) {
        for (int e = t; e < 64 * 32; e += 256) {
            int r = e >> 5, kk = e & 31;
            int kg = k0 + kk;
            float v = (kg < K) ? A[(size_t)(r0 + r) * lda + kg] : 0.f;
            At[kk * 68 + r] = v;
        }
        for (int e = t; e < 32 * 16; e += 256) {
            int kk = e >> 4, c4 = (e & 15) << 2;
            int kg = k0 + kk;
            float4 v = {0.f, 0.f, 0.f, 0.f};
            if (kg < K) v = *(const float4*)&Bt[(size_t)kg * ldb + c0 + c4];
            *(float4*)&Bs[kk * 68 + c4] = v;
        }
        __syncthreads();
        for (int kk = 0; kk < 32; ++kk) {
            float4 av = *(float4*)&At[kk * 68 + tr * 4];
            float4 bv = *(float4*)&Bs[kk * 68 + tc * 4];
            const float* ap = (const float*)&av;
            const float* bp = (const float*)&bv;
            #pragma unroll
            for (int j = 0; j < 4; ++j)
                #pragma unroll
                for (int i = 0; i < 4; ++i) acc[j][i] += ap[j] * bp[i];
        }
        __syncthreads();
    }

    #pragma unroll
    for (int j = 0; j < 4; ++j) {
        size_t r = r0 + tr * 4 + j;
        float4 v; v.x = acc[j][0]; v.y = acc[j][1]; v.z = acc[j][2]; v.w = acc[j][3];
        *(float4*)&D[r * ldd + c0 + tc * 4] = v;
    }
}

__global__ void k_gather_max(const float* __restrict__ dot, const int* __restrict__ idxg,
                             float* __restrict__ acto, int O, int ostride, int ocol0) {
    int i = blockIdx.x * 256 + threadIdx.x;
    if (i >= B_ * N_ * O) return;
    int o  = i % O;
    int rn = i / O;
    int b  = rn >> 11;
    const int* ip = idxg + (size_t)rn * 4;
    int twoO = O * 2;
    size_t bbase = (size_t)b * N_ * twoO;
    float ctr = dot[(size_t)rn * twoO + O + o];
    float m0 = dot[bbase + (size_t)ip[0] * twoO + o];
    float m1 = dot[bbase + (size_t)ip[1] * twoO + o];
    float m2 = dot[bbase + (size_t)ip[2] * twoO + o];
    float m3 = dot[bbase + (size_t)ip[3] * twoO + o];
    float mx = fmaxf(fmaxf(m0, m1), fmaxf(m2, m3));
    acto[(size_t)rn * ostride + ocol0 + o] = fmaxf(mx + ctr, 0.f);
}

__global__ void k_feat_bf16(const float* __restrict__ x1, const float* __restrict__ x2,
                            const float* __restrict__ x3, const float* __restrict__ x4,
                            u16* __restrict__ fb) {
    int i = blockIdx.x * 256 + threadIdx.x;
    if (i >= B_ * N_ * 512 / 8) return;
    int rn = i >> 6, c8 = (i & 63) << 3;
    const float* src;
    if      (c8 < 64)  src = x1 + (size_t)rn * 64  + c8;
    else if (c8 < 128) src = x2 + (size_t)rn * 64  + (c8 - 64);
    else if (c8 < 256) src = x3 + (size_t)rn * 128 + (c8 - 128);
    else               src = x4 + (size_t)rn * 256 + (c8 - 256);
    float4 va = *(const float4*)src;
    float4 vb = *(const float4*)(src + 4);
    uint4 u;
    u.x = ((unsigned)f2bf(va.y) << 16) | f2bf(va.x);
    u.y = ((unsigned)f2bf(va.w) << 16) | f2bf(va.z);
    u.z = ((unsigned)f2bf(vb.y) << 16) | f2bf(vb.x);
    u.w = ((unsigned)f2bf(vb.w) << 16) | f2bf(vb.z);
    *(uint4*)&fb[(size_t)i * 8] = u;
}

__global__ void k_w5_bf16(const float* __restrict__ W5, u16* __restrict__ wb) {
    int i = blockIdx.x * 256 + threadIdx.x;
    if (i >= 512 * 512 / 8) return;
    const float* src = W5 + (size_t)i * 8;
    float4 va = *(const float4*)src;
    float4 vb = *(const float4*)(src + 4);
    uint4 u;
    u.x = ((unsigned)f2bf(va.y) << 16) | f2bf(va.x);
    u.y = ((unsigned)f2bf(va.w) << 16) | f2bf(va.z);
    u.z = ((unsigned)f2bf(vb.y) << 16) | f2bf(vb.x);
    u.w = ((unsigned)f2bf(vb.w) << 16) | f2bf(vb.z);
    *(uint4*)&wb[(size_t)i * 8] = u;
}

__global__ __launch_bounds__(256) void k_mfma_final(
    const u16* __restrict__ Ab, const u16* __restrict__ Bb, float* __restrict__ out)
{
    __shared__ u16 As[128 * 40];
    __shared__ u16 Bs[128 * 40];
    const int bn0 = blockIdx.x * 128;
    const int o0  = blockIdx.y * 128;
    const int t    = threadIdx.x;
    const int w    = t >> 6;
    const int lane = t & 63;
    const int wm = w >> 1, wn = w & 1;
    const int l15 = lane & 15, l4 = lane >> 4;

    f32x4 acc[4][4];
    #pragma unroll
    for (int mi = 0; mi < 4; ++mi)
        #pragma unroll
        for (int ni = 0; ni < 4; ++ni) acc[mi][ni] = (f32x4){0.f, 0.f, 0.f, 0.f};

    for (int k0 = 0; k0 < 512; k0 += 32) {
        __syncthreads();
        for (int e = t; e < 128 * 4; e += 256) {
            int row = e >> 2, q = e & 3;
            *(float4*)&As[row * 40 + q * 8] =
                *(const float4*)&Ab[(size_t)(o0 + row) * 512 + k0 + q * 8];
            *(float4*)&Bs[row * 40 + q * 8] =
                *(const float4*)&Bb[(size_t)(bn0 + row) * 512 + k0 + q * 8];
        }
        __syncthreads();
        bf16x8 af[4], bf[4];
        #pragma unroll
        for (int mi = 0; mi < 4; ++mi)
            af[mi] = *(const bf16x8*)&As[(wm * 64 + mi * 16 + l15) * 40 + l4 * 8];
        #pragma unroll
        for (int ni = 0; ni < 4; ++ni)
            bf[ni] = *(const bf16x8*)&Bs[(wn * 64 + ni * 16 + l15) * 40 + l4 * 8];
        #pragma unroll
        for (int mi = 0; mi < 4; ++mi)
            #pragma unroll
            for (int ni = 0; ni < 4; ++ni)
                acc[mi][ni] = __builtin_amdgcn_mfma_f32_16x16x32_bf16(
                    af[mi], bf[ni], acc[mi][ni], 0, 0, 0);
    }

    const int bidx = bn0 >> 11;
    const int nloc = bn0 & (N_ - 1);
    #pragma unroll
    for (int mi = 0; mi < 4; ++mi)
        #pragma unroll
        for (int ni = 0; ni < 4; ++ni) {
            int o = o0 + wm * 64 + mi * 16 + l4 * 4;
            int n = nloc + wn * 64 + ni * 16 + l15;
            #pragma unroll
            for (int r = 0; r < 4; ++r)
                out[((size_t)bidx * 512 + o + r) * N_ + n] = acc[mi][ni][r];
        }
}

extern "C" void kernel_launch(void* const* d_in, const int* in_sizes, int n_in,
                              void* d_out, int out_size, void* d_ws, size_t ws_size,
                              hipStream_t stream) {
    const float* x  = (const float*)d_in[0];
    const float* W1 = (const float*)d_in[1];
    const float* W2 = (const float*)d_in[2];
    const float* W3 = (const float*)d_in[3];
    const float* W4 = (const float*)d_in[4];
    const float* W5 = (const float*)d_in[5];

    // 49.5 MiB layout (known-good).
    float* ws  = (float*)d_ws;
    float* x1  = ws;                          // 16384*64
    float* x2  = x1 + 1048576;                // 16384*64
    float* x3  = x2 + 1048576;                // 16384*128
    float* x4  = x3 + 2097152;                // 16384*256
    float* dot = x4 + 4194304;                // 4,194,304 floats
    float* xt0 = dot + 4194304;               // 49152
    float* sq  = xt0 + 49152;                 // 16384
    int*   idx = (int*)(sq + 16384);          // 65536 ints
    float* wt  = sq + 16384 + 65536;          // max 128*512
    // dot-region overlays during knn (dead until conv GEMM); sums to 4,194,304 f
    u16*   xh   = (u16*)dot;
    u16*   xmd  = (u16*)(dot + 1048576);
    u16*   xl   = (u16*)(dot + 2097152);
    float* pval = dot + 3145728;              // 16384*32 f32
    int*   pidx = (int*)(dot + 3670016);      // 16384*32 int
    u16*   featb = (u16*)dot;                 // final-layer overlay
    u16*   w5b   = (u16*)xt0;                 // over xt0/sq/idx

    k_transpose_x<<<64, 256, 0, stream>>>(x, xt0);
    const int knn_grid = B_ * 16 * SEG;       // 1024

    // ---- layer 1: C=3 (CP=32), O=64 ----
    {
        const float* actin = xt0; int C = 3, O = 64, ncols = 2 * O;
        k_sqnorm<<<64, 256, 0, stream>>>(actin, sq, C);
        k_split3<3, 32><<<(B_ * N_ * 32 / 8 + 255) / 256, 256, 0, stream>>>(actin, xh, xmd, xl);
        k_knn_mfma<32><<<knn_grid, 256, 0, stream>>>(xh, xmd, xl, sq, pval, pidx);
        k_knn_merge<<<64, 256, 0, stream>>>(pval, pidx, idx);
        k_pack_w<<<(C * ncols + 255) / 256, 256, 0, stream>>>(W1, wt, O, C, ncols, 2 * C, 0);
        dim3 g((B_ * N_) / 64, ncols / 64);
        k_gemm<<<g, 256, 0, stream>>>(actin, C, wt, ncols, dot, ncols, C);
        k_gather_max<<<(B_ * N_ * O + 255) / 256, 256, 0, stream>>>(dot, idx, x1, O, O, 0);
    }
    // ---- layer 2: C=64, O=64 ----
    {
        const float* actin = x1; int C = 64, O = 64, ncols = 2 * O;
        k_sqnorm<<<64, 256, 0, stream>>>(actin, sq, C);
        k_split3<64, 64><<<(B_ * N_ * 64 / 8 + 255) / 256, 256, 0, stream>>>(actin, xh, xmd, xl);
        k_knn_mfma<64><<<knn_grid, 256, 0, stream>>>(xh, xmd, xl, sq, pval, pidx);
        k_knn_merge<<<64, 256, 0, stream>>>(pval, pidx, idx);
        k_pack_w<<<(C * ncols + 255) / 256, 256, 0, stream>>>(W2, wt, O, C, ncols, 2 * C, 0);
        dim3 g((B_ * N_) / 64, ncols / 64);
        k_gemm<<<g, 256, 0, stream>>>(actin, C, wt, ncols, dot, ncols, C);
        k_gather_max<<<(B_ * N_ * O + 255) / 256, 256, 0, stream>>>(dot, idx, x2, O, O, 0);
    }
    // ---- layer 3: C=64, O=128 ----
    {
        const float* actin = x2; int C = 64, O = 128, ncols = 2 * O;
        k_sqnorm<<<64, 256, 0, stream>>>(actin, sq, C);
        k_split3<64, 64><<<(B_ * N_ * 64 / 8 + 255) / 256, 256, 0, stream>>>(actin, xh, xmd, xl);
        k_knn_mfma<64><<<knn_grid, 256, 0, stream>>>(xh, xmd, xl, sq, pval, pidx);
        k_knn_merge<<<64, 256, 0, stream>>>(pval, pidx, idx);
        k_pack_w<<<(C * ncols + 255) / 256, 256, 0, stream>>>(W3, wt, O, C, ncols, 2 * C, 0);
        dim3 g((B_ * N_) / 64, ncols / 64);
        k_gemm<<<g, 256, 0, stream>>>(actin, C, wt, ncols, dot, ncols, C);
        k_gather_max<<<(B_ * N_ * O + 255) / 256, 256, 0, stream>>>(dot, idx, x3, O, O, 0);
    }
    // ---- layer 4: C=128, O=256 — two 128-output halves ----
    {
        const float* actin = x3; int C = 128;
        k_sqnorm<<<64, 256, 0, stream>>>(actin, sq, C);
        k_split3<128, 128><<<(B_ * N_ * 128 / 8 + 255) / 256, 256, 0, stream>>>(actin, xh, xmd, xl);
        k_knn_mfma<128><<<knn_grid, 256, 0, stream>>>(xh, xmd, xl, sq, pval, pidx);
        k_knn_merge<<<64, 256, 0, stream>>>(pval, pidx, idx);
        for (int oh = 0; oh < 2; ++oh) {
            int Oh = 128, ncols = 2 * Oh, o0 = oh * 128;
            k_pack_w<<<(C * ncols + 255) / 256, 256, 0, stream>>>(W4, wt, Oh, C, ncols, 2 * C, o0);
            dim3 g((B_ * N_) / 64, ncols / 64);
            k_gemm<<<g, 256, 0, stream>>>(actin, C, wt, ncols, dot, ncols, C);
            k_gather_max<<<(B_ * N_ * Oh + 255) / 256, 256, 0, stream>>>(dot, idx, x4, Oh, 256, o0);
        }
    }

    // ---- final: out = W5 * concat(x1..x4) via bf16 MFMA, f32 out (B,512,N) ----
    k_feat_bf16<<<(B_ * N_ * 512 / 8 + 255) / 256, 256, 0, stream>>>(x1, x2, x3, x4, featb);
    k_w5_bf16<<<(512 * 512 / 8 + 255) / 256, 256, 0, stream>>>(W5, w5b);
    dim3 gm(B_ * N_ / 128, 512 / 128);
    k_mfma_final<<<gm, 256, 0, stream>>>(w5b, featb, (float*)d_out);
}

// Round 11
// 484.260 us; speedup vs baseline: 2.0627x; 1.1085x over previous
//
#include <hip/hip_runtime.h>
#include <hip/hip_bf16.h>

#define B_ 8
#define N_ 2048
#define SEG 8
#define TMM 64    // knn m-rows per tile-iter
#define TNN 128   // knn n-cols per block

typedef __bf16 bf16x8 __attribute__((ext_vector_type(8)));
typedef float  f32x4  __attribute__((ext_vector_type(4)));
typedef unsigned short u16;

__device__ __forceinline__ u16 f2bf(float f) {
    __hip_bfloat16 h = __float2bfloat16(f);
    return *reinterpret_cast<u16*>(&h);
}
__device__ __forceinline__ float bf2f(u16 u) {
    unsigned v = ((unsigned)u) << 16;
    return *reinterpret_cast<float*>(&v);
}

__global__ void k_transpose_x(const float* __restrict__ x, float* __restrict__ xt) {
    int i = blockIdx.x * 256 + threadIdx.x;
    if (i >= B_ * N_) return;
    int b = i >> 11, n = i & (N_ - 1);
    const float* src = x + (size_t)b * 3 * N_ + n;
    float* dst = xt + (size_t)i * 3;
    dst[0] = src[0];
    dst[1] = src[N_];
    dst[2] = src[2 * N_];
}

__global__ void k_sqnorm(const float* __restrict__ act, float* __restrict__ sq, int C) {
    int i = blockIdx.x * 256 + threadIdx.x;
    if (i >= B_ * N_) return;
    const float* r = act + (size_t)i * C;
    float s = 0.f;
    for (int c = 0; c < C; ++c) s += r[c] * r[c];
    sq[i] = s;
}

// 3-term bf16 split: x = hi + mid + lo (exact residuals, RNE). Pad k>=C with 0.
// R9 lesson: 2-term (4-product, ~7.6e-6) FLIPS NEIGHBORS; 3-term (~1e-7) passes.
template<int C, int CP>
__global__ void k_split3(const float* __restrict__ act, u16* __restrict__ xh,
                         u16* __restrict__ xm, u16* __restrict__ xl) {
    int i = blockIdx.x * 256 + threadIdx.x;
    if (i >= B_ * N_ * CP / 8) return;
    int rn = i / (CP / 8), c8 = (i % (CP / 8)) * 8;
    u16 h[8], m[8], l[8];
    #pragma unroll
    for (int j = 0; j < 8; ++j) {
        int c = c8 + j;
        float x = (c < C) ? act[(size_t)rn * C + c] : 0.f;
        u16 hh = f2bf(x);
        float r1 = x - bf2f(hh);
        u16 mm = f2bf(r1);
        float r2 = r1 - bf2f(mm);
        h[j] = hh; m[j] = mm; l[j] = f2bf(r2);
    }
    *(uint4*)&xh[(size_t)i * 8] = *(uint4*)h;
    *(uint4*)&xm[(size_t)i * 8] = *(uint4*)m;
    *(uint4*)&xl[(size_t)i * 8] = *(uint4*)l;
}

// Pack W into Wo[o2][CP] (o2-major, k-contig) and 3-split, for conv MFMA B-operand.
// o2<O -> neighbor half W[orow0+o2][c]; else center half W[orow0+o2-O][C+c]. Pad c>=C.
__global__ void k_pack_wsplit3(const float* __restrict__ W, u16* __restrict__ wh,
                               u16* __restrict__ wm, u16* __restrict__ wl,
                               int O, int C, int CP, int ncols, int wrow, int orow0) {
    int i = blockIdx.x * 256 + threadIdx.x;
    if (i >= ncols * CP) return;
    int o2 = i / CP, c = i % CP;
    int o   = ((o2 < O) ? o2 : o2 - O) + orow0;
    int col = (o2 < O) ? c : (C + c);
    float v = (c < C) ? W[(size_t)o * wrow + col] : 0.f;
    u16 hh = f2bf(v);
    float r1 = v - bf2f(hh);
    u16 mm = f2bf(r1);
    float r2 = r1 - bf2f(mm);
    wh[i] = hh; wm[i] = mm; wl[i] = f2bf(r2);
}

__device__ __forceinline__ void ins4(float& v0, float& v1, float& v2, float& v3,
                                     int& i0, int& i1, int& i2, int& i3,
                                     float p, int m) {
    bool g3 = p > v3, g2 = p > v2, g1 = p > v1, g0 = p > v0;
    v3 = g2 ? v2 : (g3 ? p : v3); i3 = g2 ? i2 : (g3 ? m : i3);
    v2 = g1 ? v1 : (g2 ? p : v2); i2 = g1 ? i1 : (g2 ? m : i2);
    v1 = g0 ? v0 : (g1 ? p : v1); i1 = g0 ? i0 : (g1 ? m : i1);
    v0 = g0 ? p  : v0;            i0 = g0 ? m  : i0;
}

// knn via 3-term-split MFMA (6 products: hh,hm,mh,mm,hl,lh) — R8 proven, verbatim.
template<int CP>
__global__ __launch_bounds__(256) void k_knn_mfma(
    const u16* __restrict__ xh, const u16* __restrict__ xmd, const u16* __restrict__ xl,
    const float* __restrict__ sqg, float* __restrict__ pval, int* __restrict__ pidx)
{
    __shared__ __align__(16) u16 sm[3 * TNN * 40 + 3 * TMM * 40];
    __shared__ float sqm_l[TMM];
    u16* Anh = sm;
    u16* Anm = sm + TNN * 40;
    u16* Anl = sm + 2 * TNN * 40;
    u16* Amh = sm + 3 * TNN * 40;
    u16* Amm = Amh + TMM * 40;
    u16* Aml = Amh + 2 * TMM * 40;

    const int bid = blockIdx.x;
    const int seg = bid & (SEG - 1);
    const int nb  = (bid >> 3) & 15;
    const int b   = bid >> 7;
    const int n0  = nb * TNN;
    const int t    = threadIdx.x;
    const int w    = t >> 6, lane = t & 63;
    const int wm = w >> 1, wn = w & 1;
    const int l15 = lane & 15, l4 = lane >> 4;
    const size_t rowbase = (size_t)b * N_;

    float tv[4][4];
    int   ti[4][4];
    #pragma unroll
    for (int ni = 0; ni < 4; ++ni)
        #pragma unroll
        for (int q = 0; q < 4; ++q) { tv[ni][q] = -3.4e38f; ti[ni][q] = 0; }

    const int mstart = seg * (N_ / SEG);
    for (int m0 = mstart; m0 < mstart + N_ / SEG; m0 += TMM) {
        f32x4 acc[2][4];
        #pragma unroll
        for (int mi = 0; mi < 2; ++mi)
            #pragma unroll
            for (int ni = 0; ni < 4; ++ni) acc[mi][ni] = (f32x4){0.f, 0.f, 0.f, 0.f};

        for (int k0 = 0; k0 < CP; k0 += 32) {
            __syncthreads();
            for (int e = t; e < TNN * 4; e += 256) {
                int row = e >> 2, q = e & 3;
                size_t g = (rowbase + n0 + row) * CP + k0 + q * 8;
                int d = row * 40 + q * 8;
                *(uint4*)&Anh[d] = *(const uint4*)&xh[g];
                *(uint4*)&Anm[d] = *(const uint4*)&xmd[g];
                *(uint4*)&Anl[d] = *(const uint4*)&xl[g];
            }
            {   // TMM*4 == 256: one per thread
                int row = t >> 2, q = t & 3;
                size_t g = (rowbase + m0 + row) * CP + k0 + q * 8;
                int d = row * 40 + q * 8;
                *(uint4*)&Amh[d] = *(const uint4*)&xh[g];
                *(uint4*)&Amm[d] = *(const uint4*)&xmd[g];
                *(uint4*)&Aml[d] = *(const uint4*)&xl[g];
            }
            if (k0 == 0 && t < TMM) sqm_l[t] = sqg[rowbase + m0 + t];
            __syncthreads();

            bf16x8 amh[2], amm[2], aml[2], bnh[4], bnm[4], bnl[4];
            #pragma unroll
            for (int mi = 0; mi < 2; ++mi) {
                int off = (wm * 32 + mi * 16 + l15) * 40 + l4 * 8;
                amh[mi] = *(const bf16x8*)&Amh[off];
                amm[mi] = *(const bf16x8*)&Amm[off];
                aml[mi] = *(const bf16x8*)&Aml[off];
            }
            #pragma unroll
            for (int ni = 0; ni < 4; ++ni) {
                int off = (wn * 64 + ni * 16 + l15) * 40 + l4 * 8;
                bnh[ni] = *(const bf16x8*)&Anh[off];
                bnm[ni] = *(const bf16x8*)&Anm[off];
                bnl[ni] = *(const bf16x8*)&Anl[off];
            }
            #pragma unroll
            for (int mi = 0; mi < 2; ++mi)
                #pragma unroll
                for (int ni = 0; ni < 4; ++ni) {
                    f32x4 a = acc[mi][ni];
                    a = __builtin_amdgcn_mfma_f32_16x16x32_bf16(amh[mi], bnh[ni], a, 0, 0, 0);
                    a = __builtin_amdgcn_mfma_f32_16x16x32_bf16(amh[mi], bnm[ni], a, 0, 0, 0);
                    a = __builtin_amdgcn_mfma_f32_16x16x32_bf16(amm[mi], bnh[ni], a, 0, 0, 0);
                    a = __builtin_amdgcn_mfma_f32_16x16x32_bf16(amm[mi], bnm[ni], a, 0, 0, 0);
                    a = __builtin_amdgcn_mfma_f32_16x16x32_bf16(amh[mi], bnl[ni], a, 0, 0, 0);
                    a = __builtin_amdgcn_mfma_f32_16x16x32_bf16(aml[mi], bnh[ni], a, 0, 0, 0);
                    acc[mi][ni] = a;
                }
        }
        #pragma unroll
        for (int ni = 0; ni < 4; ++ni)
            #pragma unroll
            for (int mi = 0; mi < 2; ++mi)
                #pragma unroll
                for (int r = 0; r < 4; ++r) {
                    int mloc = wm * 32 + mi * 16 + l4 * 4 + r;
                    float sc = 2.f * acc[mi][ni][r] - sqm_l[mloc];
                    ins4(tv[ni][0], tv[ni][1], tv[ni][2], tv[ni][3],
                         ti[ni][0], ti[ni][1], ti[ni][2], ti[ni][3], sc, m0 + mloc);
                }
    }

    __syncthreads();
    float* sv = (float*)sm;            // [2][128][4] val
    int*   si = (int*)sm + 1024;       // [2][128][4] idx
    #pragma unroll
    for (int ni = 0; ni < 4; ++ni) {
        float v0 = tv[ni][0], v1 = tv[ni][1], v2 = tv[ni][2], v3 = tv[ni][3];
        int   i0 = ti[ni][0], i1 = ti[ni][1], i2 = ti[ni][2], i3 = ti[ni][3];
        #pragma unroll
        for (int st = 16; st < 64; st <<= 1) {
            float w0 = __shfl_xor(v0, st), w1 = __shfl_xor(v1, st);
            float w2 = __shfl_xor(v2, st), w3 = __shfl_xor(v3, st);
            int   j0 = __shfl_xor(i0, st), j1 = __shfl_xor(i1, st);
            int   j2 = __shfl_xor(i2, st), j3 = __shfl_xor(i3, st);
            ins4(v0, v1, v2, v3, i0, i1, i2, i3, w0, j0);
            ins4(v0, v1, v2, v3, i0, i1, i2, i3, w1, j1);
            ins4(v0, v1, v2, v3, i0, i1, i2, i3, w2, j2);
            ins4(v0, v1, v2, v3, i0, i1, i2, i3, w3, j3);
        }
        if (l4 == 0) {
            int col = wn * 64 + ni * 16 + l15;
            int base = (wm * 128 + col) * 4;
            sv[base + 0] = v0; sv[base + 1] = v1; sv[base + 2] = v2; sv[base + 3] = v3;
            si[base + 0] = i0; si[base + 1] = i1; si[base + 2] = i2; si[base + 3] = i3;
        }
    }
    __syncthreads();
    if (t < 128) {
        int b0 = t * 4, b1 = (128 + t) * 4;
        float v0 = sv[b0], v1 = sv[b0 + 1], v2 = sv[b0 + 2], v3 = sv[b0 + 3];
        int   i0 = si[b0], i1 = si[b0 + 1], i2 = si[b0 + 2], i3 = si[b0 + 3];
        #pragma unroll
        for (int q = 0; q < 4; ++q)
            ins4(v0, v1, v2, v3, i0, i1, i2, i3, sv[b1 + q], si[b1 + q]);
        size_t pb = (rowbase + n0 + t) * (SEG * 4) + seg * 4;
        pval[pb + 0] = v0; pval[pb + 1] = v1; pval[pb + 2] = v2; pval[pb + 3] = v3;
        pidx[pb + 0] = i0; pidx[pb + 1] = i1; pidx[pb + 2] = i2; pidx[pb + 3] = i3;
    }
}

__global__ void k_knn_merge(const float* __restrict__ pval, const int* __restrict__ pidx,
                            int* __restrict__ idxo) {
    int rn = blockIdx.x * 256 + threadIdx.x;
    if (rn >= B_ * N_) return;
    const float* pv = pval + (size_t)rn * (SEG * 4);
    const int*   pi = pidx + (size_t)rn * (SEG * 4);
    float v0 = pv[0], v1 = pv[1], v2 = pv[2], v3 = pv[3];
    int   i0 = pi[0], i1 = pi[1], i2 = pi[2], i3 = pi[3];
    for (int s = 1; s < SEG; ++s)
        #pragma unroll
        for (int q = 0; q < 4; ++q)
            ins4(v0, v1, v2, v3, i0, i1, i2, i3, pv[s * 4 + q], pi[s * 4 + q]);
    int* op = idxo + (size_t)rn * 4;
    op[0] = i0; op[1] = i1; op[2] = i2; op[3] = i3;
}

// Conv GEMM via 3-term-split MFMA (same 6 products as knn — ~1e-7 rel error).
// D[bn][o2] = sum_c act[bn][c] * Wo[o2][c]; A = act splits (SHARED with knn),
// B = Wo splits. Block 128bn x 128o2, 4 waves 2x2; f32 row-major store (ld=ncols).
template<int CP>
__global__ __launch_bounds__(256) void k_conv_mfma(
    const u16* __restrict__ xh, const u16* __restrict__ xmd, const u16* __restrict__ xl,
    const u16* __restrict__ wh, const u16* __restrict__ wmm, const u16* __restrict__ wl,
    float* __restrict__ D, int ncols)
{
    __shared__ __align__(16) u16 sm[6 * 128 * 40];
    u16* Ah = sm;
    u16* Am = sm + 128 * 40;
    u16* Al = sm + 2 * 128 * 40;
    u16* Bh = sm + 3 * 128 * 40;
    u16* Bm = sm + 4 * 128 * 40;
    u16* Bl = sm + 5 * 128 * 40;

    const int bn0 = blockIdx.x * 128;
    const int o0  = blockIdx.y * 128;
    const int t    = threadIdx.x;
    const int w    = t >> 6, lane = t & 63;
    const int wm = w >> 1, wn = w & 1;
    const int l15 = lane & 15, l4 = lane >> 4;

    f32x4 acc[4][4];
    #pragma unroll
    for (int mi = 0; mi < 4; ++mi)
        #pragma unroll
        for (int ni = 0; ni < 4; ++ni) acc[mi][ni] = (f32x4){0.f, 0.f, 0.f, 0.f};

    for (int k0 = 0; k0 < CP; k0 += 32) {
        __syncthreads();
        for (int e = t; e < 128 * 4; e += 256) {
            int row = e >> 2, q = e & 3;
            int d = row * 40 + q * 8;
            size_t ga = (size_t)(bn0 + row) * CP + k0 + q * 8;
            size_t gb = (size_t)(o0 + row) * CP + k0 + q * 8;
            *(uint4*)&Ah[d] = *(const uint4*)&xh[ga];
            *(uint4*)&Am[d] = *(const uint4*)&xmd[ga];
            *(uint4*)&Al[d] = *(const uint4*)&xl[ga];
            *(uint4*)&Bh[d] = *(const uint4*)&wh[gb];
            *(uint4*)&Bm[d] = *(const uint4*)&wmm[gb];
            *(uint4*)&Bl[d] = *(const uint4*)&wl[gb];
        }
        __syncthreads();
        bf16x8 ah[4], am[4], al[4], bh[4], bm[4], bl[4];
        #pragma unroll
        for (int mi = 0; mi < 4; ++mi) {
            int off = (wm * 64 + mi * 16 + l15) * 40 + l4 * 8;
            ah[mi] = *(const bf16x8*)&Ah[off];
            am[mi] = *(const bf16x8*)&Am[off];
            al[mi] = *(const bf16x8*)&Al[off];
        }
        #pragma unroll
        for (int ni = 0; ni < 4; ++ni) {
            int off = (wn * 64 + ni * 16 + l15) * 40 + l4 * 8;
            bh[ni] = *(const bf16x8*)&Bh[off];
            bm[ni] = *(const bf16x8*)&Bm[off];
            bl[ni] = *(const bf16x8*)&Bl[off];
        }
        #pragma unroll
        for (int mi = 0; mi < 4; ++mi)
            #pragma unroll
            for (int ni = 0; ni < 4; ++ni) {
                f32x4 a = acc[mi][ni];
                a = __builtin_amdgcn_mfma_f32_16x16x32_bf16(ah[mi], bh[ni], a, 0, 0, 0);
                a = __builtin_amdgcn_mfma_f32_16x16x32_bf16(ah[mi], bm[ni], a, 0, 0, 0);
                a = __builtin_amdgcn_mfma_f32_16x16x32_bf16(am[mi], bh[ni], a, 0, 0, 0);
                a = __builtin_amdgcn_mfma_f32_16x16x32_bf16(am[mi], bm[ni], a, 0, 0, 0);
                a = __builtin_amdgcn_mfma_f32_16x16x32_bf16(ah[mi], bl[ni], a, 0, 0, 0);
                a = __builtin_amdgcn_mfma_f32_16x16x32_bf16(al[mi], bh[ni], a, 0, 0, 0);
                acc[mi][ni] = a;
            }
    }

    #pragma unroll
    for (int mi = 0; mi < 4; ++mi)
        #pragma unroll
        for (int ni = 0; ni < 4; ++ni) {
            int bnl_ = wm * 64 + mi * 16 + l4 * 4;
            int o2  = o0 + wn * 64 + ni * 16 + l15;
            #pragma unroll
            for (int r = 0; r < 4; ++r)
                D[(size_t)(bn0 + bnl_ + r) * ncols + o2] = acc[mi][ni][r];
        }
}

__global__ void k_gather_max(const float* __restrict__ dot, const int* __restrict__ idxg,
                             float* __restrict__ acto, int O, int ostride, int ocol0) {
    int i = blockIdx.x * 256 + threadIdx.x;
    if (i >= B_ * N_ * O) return;
    int o  = i % O;
    int rn = i / O;
    int b  = rn >> 11;
    const int* ip = idxg + (size_t)rn * 4;
    int twoO = O * 2;
    size_t bbase = (size_t)b * N_ * twoO;
    float ctr = dot[(size_t)rn * twoO + O + o];
    float m0 = dot[bbase + (size_t)ip[0] * twoO + o];
    float m1 = dot[bbase + (size_t)ip[1] * twoO + o];
    float m2 = dot[bbase + (size_t)ip[2] * twoO + o];
    float m3 = dot[bbase + (size_t)ip[3] * twoO + o];
    float mx = fmaxf(fmaxf(m0, m1), fmaxf(m2, m3));
    acto[(size_t)rn * ostride + ocol0 + o] = fmaxf(mx + ctr, 0.f);
}

__global__ void k_feat_bf16(const float* __restrict__ x1, const float* __restrict__ x2,
                            const float* __restrict__ x3, const float* __restrict__ x4,
                            u16* __restrict__ fb) {
    int i = blockIdx.x * 256 + threadIdx.x;
    if (i >= B_ * N_ * 512 / 8) return;
    int rn = i >> 6, c8 = (i & 63) << 3;
    const float* src;
    if      (c8 < 64)  src = x1 + (size_t)rn * 64  + c8;
    else if (c8 < 128) src = x2 + (size_t)rn * 64  + (c8 - 64);
    else if (c8 < 256) src = x3 + (size_t)rn * 128 + (c8 - 128);
    else               src = x4 + (size_t)rn * 256 + (c8 - 256);
    float4 va = *(const float4*)src;
    float4 vb = *(const float4*)(src + 4);
    uint4 u;
    u.x = ((unsigned)f2bf(va.y) << 16) | f2bf(va.x);
    u.y = ((unsigned)f2bf(va.w) << 16) | f2bf(va.z);
    u.z = ((unsigned)f2bf(vb.y) << 16) | f2bf(vb.x);
    u.w = ((unsigned)f2bf(vb.w) << 16) | f2bf(vb.z);
    *(uint4*)&fb[(size_t)i * 8] = u;
}

__global__ void k_w5_bf16(const float* __restrict__ W5, u16* __restrict__ wb) {
    int i = blockIdx.x * 256 + threadIdx.x;
    if (i >= 512 * 512 / 8) return;
    const float* src = W5 + (size_t)i * 8;
    float4 va = *(const float4*)src;
    float4 vb = *(const float4*)(src + 4);
    uint4 u;
    u.x = ((unsigned)f2bf(va.y) << 16) | f2bf(va.x);
    u.y = ((unsigned)f2bf(va.w) << 16) | f2bf(va.z);
    u.z = ((unsigned)f2bf(vb.y) << 16) | f2bf(vb.x);
    u.w = ((unsigned)f2bf(vb.w) << 16) | f2bf(vb.z);
    *(uint4*)&wb[(size_t)i * 8] = u;
}

__global__ __launch_bounds__(256) void k_mfma_final(
    const u16* __restrict__ Ab, const u16* __restrict__ Bb, float* __restrict__ out)
{
    __shared__ u16 As[128 * 40];
    __shared__ u16 Bs[128 * 40];
    const int bn0 = blockIdx.x * 128;
    const int o0  = blockIdx.y * 128;
    const int t    = threadIdx.x;
    const int w    = t >> 6;
    const int lane = t & 63;
    const int wm = w >> 1, wn = w & 1;
    const int l15 = lane & 15, l4 = lane >> 4;

    f32x4 acc[4][4];
    #pragma unroll
    for (int mi = 0; mi < 4; ++mi)
        #pragma unroll
        for (int ni = 0; ni < 4; ++ni) acc[mi][ni] = (f32x4){0.f, 0.f, 0.f, 0.f};

    for (int k0 = 0; k0 < 512; k0 += 32) {
        __syncthreads();
        for (int e = t; e < 128 * 4; e += 256) {
            int row = e >> 2, q = e & 3;
            *(float4*)&As[row * 40 + q * 8] =
                *(const float4*)&Ab[(size_t)(o0 + row) * 512 + k0 + q * 8];
            *(float4*)&Bs[row * 40 + q * 8] =
                *(const float4*)&Bb[(size_t)(bn0 + row) * 512 + k0 + q * 8];
        }
        __syncthreads();
        bf16x8 af[4], bf[4];
        #pragma unroll
        for (int mi = 0; mi < 4; ++mi)
            af[mi] = *(const bf16x8*)&As[(wm * 64 + mi * 16 + l15) * 40 + l4 * 8];
        #pragma unroll
        for (int ni = 0; ni < 4; ++ni)
            bf[ni] = *(const bf16x8*)&Bs[(wn * 64 + ni * 16 + l15) * 40 + l4 * 8];
        #pragma unroll
        for (int mi = 0; mi < 4; ++mi)
            #pragma unroll
            for (int ni = 0; ni < 4; ++ni)
                acc[mi][ni] = __builtin_amdgcn_mfma_f32_16x16x32_bf16(
                    af[mi], bf[ni], acc[mi][ni], 0, 0, 0);
    }

    const int bidx = bn0 >> 11;
    const int nloc = bn0 & (N_ - 1);
    #pragma unroll
    for (int mi = 0; mi < 4; ++mi)
        #pragma unroll
        for (int ni = 0; ni < 4; ++ni) {
            int o = o0 + wm * 64 + mi * 16 + l4 * 4;
            int n = nloc + wn * 64 + ni * 16 + l15;
            #pragma unroll
            for (int r = 0; r < 4; ++r)
                out[((size_t)bidx * 512 + o + r) * N_ + n] = acc[mi][ni][r];
        }
}

extern "C" void kernel_launch(void* const* d_in, const int* in_sizes, int n_in,
                              void* d_out, int out_size, void* d_ws, size_t ws_size,
                              hipStream_t stream) {
    const float* x  = (const float*)d_in[0];
    const float* W1 = (const float*)d_in[1];
    const float* W2 = (const float*)d_in[2];
    const float* W3 = (const float*)d_in[3];
    const float* W4 = (const float*)d_in[4];
    const float* W5 = (const float*)d_in[5];

    // 49.5 MiB ws layout (known-good). dot now lives in d_out (32 MB scratch,
    // dead until final GEMM overwrites it) so conv can consume the knn splits.
    float* ws  = (float*)d_ws;
    float* x1  = ws;                          // 16384*64
    float* x2  = x1 + 1048576;                // 16384*64
    float* x3  = x2 + 1048576;                // 16384*128
    float* x4  = x3 + 2097152;                // 16384*256
    float* dreg = x4 + 4194304;               // 4,194,304 floats (split region)
    float* xt0 = dreg + 4194304;              // 49152
    float* sq  = xt0 + 49152;                 // 16384
    int*   idx = (int*)(sq + 16384);          // 65536 ints
    float* wt  = sq + 16384 + 65536;          // >= 262144 f (1 MB)
    // split-region overlays (R8-proven): 3 act-split arrays + per-seg partials
    u16*   xh   = (u16*)dreg;                 // 16384*CP bf16 (<=4 MB)
    u16*   xmd  = (u16*)(dreg + 1048576);
    u16*   xl   = (u16*)(dreg + 2097152);
    float* pval = dreg + 3145728;             // 16384*32 f32
    int*   pidx = (int*)(dreg + 3670016);     // 16384*32 int
    u16*   featb = (u16*)dreg;                // final-layer overlay
    u16*   w5b   = (u16*)xt0;                 // over xt0/sq/idx (512 KB)
    // W-split arrays in wt region (<= 3 * 512*128*2B = 384 KB)
    u16*   woh = (u16*)wt;
    u16*   wom = woh + 65536;
    u16*   wol = wom + 65536;
    float* dot = (float*)d_out;               // conv output scratch (<=32 MB)

    k_transpose_x<<<64, 256, 0, stream>>>(x, xt0);
    const int knn_grid = B_ * 16 * SEG;       // 1024

    // ---- layer 1: C=3 (CP=32), O=64 ----
    {
        const float* actin = xt0; int C = 3, O = 64, ncols = 2 * O, CP = 32;
        k_sqnorm<<<64, 256, 0, stream>>>(actin, sq, C);
        k_split3<3, 32><<<(B_ * N_ * 32 / 8 + 255) / 256, 256, 0, stream>>>(actin, xh, xmd, xl);
        k_knn_mfma<32><<<knn_grid, 256, 0, stream>>>(xh, xmd, xl, sq, pval, pidx);
        k_knn_merge<<<64, 256, 0, stream>>>(pval, pidx, idx);
        k_pack_wsplit3<<<(ncols * CP + 255) / 256, 256, 0, stream>>>(W1, woh, wom, wol,
                                                                     O, C, CP, ncols, 2 * C, 0);
        dim3 g((B_ * N_) / 128, ncols / 128);
        k_conv_mfma<32><<<g, 256, 0, stream>>>(xh, xmd, xl, woh, wom, wol, dot, ncols);
        k_gather_max<<<(B_ * N_ * O + 255) / 256, 256, 0, stream>>>(dot, idx, x1, O, O, 0);
    }
    // ---- layer 2: C=64, O=64 ----
    {
        const float* actin = x1; int C = 64, O = 64, ncols = 2 * O, CP = 64;
        k_sqnorm<<<64, 256, 0, stream>>>(actin, sq, C);
        k_split3<64, 64><<<(B_ * N_ * 64 / 8 + 255) / 256, 256, 0, stream>>>(actin, xh, xmd, xl);
        k_knn_mfma<64><<<knn_grid, 256, 0, stream>>>(xh, xmd, xl, sq, pval, pidx);
        k_knn_merge<<<64, 256, 0, stream>>>(pval, pidx, idx);
        k_pack_wsplit3<<<(ncols * CP + 255) / 256, 256, 0, stream>>>(W2, woh, wom, wol,
                                                                     O, C, CP, ncols, 2 * C, 0);
        dim3 g((B_ * N_) / 128, ncols / 128);
        k_conv_mfma<64><<<g, 256, 0, stream>>>(xh, xmd, xl, woh, wom, wol, dot, ncols);
        k_gather_max<<<(B_ * N_ * O + 255) / 256, 256, 0, stream>>>(dot, idx, x2, O, O, 0);
    }
    // ---- layer 3: C=64, O=128 ----
    {
        const float* actin = x2; int C = 64, O = 128, ncols = 2 * O, CP = 64;
        k_sqnorm<<<64, 256, 0, stream>>>(actin, sq, C);
        k_split3<64, 64><<<(B_ * N_ * 64 / 8 + 255) / 256, 256, 0, stream>>>(actin, xh, xmd, xl);
        k_knn_mfma<64><<<knn_grid, 256, 0, stream>>>(xh, xmd, xl, sq, pval, pidx);
        k_knn_merge<<<64, 256, 0, stream>>>(pval, pidx, idx);
        k_pack_wsplit3<<<(ncols * CP + 255) / 256, 256, 0, stream>>>(W3, woh, wom, wol,
                                                                     O, C, CP, ncols, 2 * C, 0);
        dim3 g((B_ * N_) / 128, ncols / 128);
        k_conv_mfma<64><<<g, 256, 0, stream>>>(xh, xmd, xl, woh, wom, wol, dot, ncols);
        k_gather_max<<<(B_ * N_ * O + 255) / 256, 256, 0, stream>>>(dot, idx, x3, O, O, 0);
    }
    // ---- layer 4: C=128, O=256 — single full-width conv (dot = 32 MB in d_out) ----
    {
        const float* actin = x3; int C = 128, O = 256, ncols = 2 * O, CP = 128;
        k_sqnorm<<<64, 256, 0, stream>>>(actin, sq, C);
        k_split3<128, 128><<<(B_ * N_ * 128 / 8 + 255) / 256, 256, 0, stream>>>(actin, xh, xmd, xl);
        k_knn_mfma<128><<<knn_grid, 256, 0, stream>>>(xh, xmd, xl, sq, pval, pidx);
        k_knn_merge<<<64, 256, 0, stream>>>(pval, pidx, idx);
        k_pack_wsplit3<<<(ncols * CP + 255) / 256, 256, 0, stream>>>(W4, woh, wom, wol,
                                                                     O, C, CP, ncols, 2 * C, 0);
        dim3 g((B_ * N_) / 128, ncols / 128);
        k_conv_mfma<128><<<g, 256, 0, stream>>>(xh, xmd, xl, woh, wom, wol, dot, ncols);
        k_gather_max<<<(B_ * N_ * O + 255) / 256, 256, 0, stream>>>(dot, idx, x4, O, O, 0);
    }

    // ---- final: out = W5 * concat(x1..x4) via bf16 MFMA, f32 out (B,512,N) ----
    k_feat_bf16<<<(B_ * N_ * 512 / 8 + 255) / 256, 256, 0, stream>>>(x1, x2, x3, x4, featb);
    k_w5_bf16<<<(512 * 512 / 8 + 255) / 256, 256, 0, stream>>>(W5, w5b);
    dim3 gm(B_ * N_ / 128, 512 / 128);
    k_mfma_final<<<gm, 256, 0, stream>>>(w5b, featb, (float*)d_out);
}